// Round 1
// baseline (3757.912 us; speedup 1.0000x reference)
//
#include <hip/hip_runtime.h>

#define N_NODES 50000
#define N_EDGES 200000
#define DE 32
#define DH 256
#define N_FRAG 10000
#define N_GRAPH 2000

// ---------------------------------------------------------------------------
// Edge-feature aggregation (once; reused by all 3 layers):
// agg_e[dst] += relu(edge_attr[e]),  [N,32]
__global__ __launch_bounds__(256)
void edge_agg_kernel(const float* __restrict__ ea, const int* __restrict__ ei,
                     float* __restrict__ agg_e) {
    int tid = blockIdx.x * 256 + threadIdx.x;
    if (tid >= N_EDGES * 8) return;
    int e = tid >> 3;
    int j = (tid & 7) << 2;
    int dst = ei[N_EDGES + e];
    float4 v = *(const float4*)(ea + (size_t)e * DE + j);
    float* p = agg_e + (size_t)dst * DE + j;
    atomicAdd(p + 0, fmaxf(v.x, 0.f));
    atomicAdd(p + 1, fmaxf(v.y, 0.f));
    atomicAdd(p + 2, fmaxf(v.z, 0.f));
    atomicAdd(p + 3, fmaxf(v.w, 0.f));
}

// agg[n][0:din] = x[n]  (the (1+eps)*x self term, eps=0);  agg[n][din:fin] = agg_e[n]
__global__ __launch_bounds__(256)
void init_agg_kernel(const float* __restrict__ x, const float* __restrict__ agg_e,
                     float* __restrict__ agg, int din, int fin) {
    int chunks = fin >> 2;
    int tid = blockIdx.x * 256 + threadIdx.x;
    if (tid >= N_NODES * chunks) return;
    int n = tid / chunks;
    int j = (tid - n * chunks) << 2;
    float4 v;
    if (j < din) v = *(const float4*)(x + (size_t)n * din + j);
    else         v = *(const float4*)(agg_e + (size_t)n * DE + (j - din));
    *(float4*)(agg + (size_t)n * fin + j) = v;
}

// agg[dst][0:din] += relu(x[src]) for each edge
__global__ __launch_bounds__(256)
void scatter_kernel(const float* __restrict__ x, const int* __restrict__ ei,
                    float* __restrict__ agg, int din, int fin, int shift) {
    int chunks = din >> 2;
    int tid = blockIdx.x * 256 + threadIdx.x;
    if (tid >= N_EDGES * chunks) return;
    int e = tid >> shift;
    int j = (tid & (chunks - 1)) << 2;
    int src = ei[e];
    int dst = ei[N_EDGES + e];
    float4 v = *(const float4*)(x + (size_t)src * din + j);
    float* p = agg + (size_t)dst * fin + j;
    atomicAdd(p + 0, fmaxf(v.x, 0.f));
    atomicAdd(p + 1, fmaxf(v.y, 0.f));
    atomicAdd(p + 2, fmaxf(v.z, 0.f));
    atomicAdd(p + 3, fmaxf(v.w, 0.f));
}

// ---------------------------------------------------------------------------
// C[r][c] = relu(A[r][:] @ W[:][c] + bias[c]);  A: N x K (stride K), W: K x 256.
// If BN: accumulate per-channel sum / sumsq (biased batch stats) via atomics.
// Tile: 64 rows x 256 cols per block (256 thr); each thread: 16 rows x 4 cols.
template <bool BN>
__global__ __launch_bounds__(256)
void gemm_relu_kernel(const float* __restrict__ A, const float* __restrict__ W,
                      const float* __restrict__ bias, float* __restrict__ C,
                      int K, float* __restrict__ bnsum, float* __restrict__ bnsumsq) {
    __shared__ float sAT[32 * 68];   // [k][row], stride 68 (16B-aligned, low write conflicts)
    __shared__ float sW[32 * 256];   // [k][col]
    const int t = threadIdx.x;
    const int lane = t & 63;
    const int wave = t >> 6;
    const int r0 = wave << 4;        // rows r0..r0+15 of the tile
    const int c4 = lane << 2;        // cols c4..c4+3
    const int row0 = blockIdx.x << 6;
    const int r = t >> 3;            // 0..31 (loader row)
    const int q = t & 7;             // 0..7  (loader k-quad)

    float acc[16][4];
#pragma unroll
    for (int i = 0; i < 16; ++i) { acc[i][0] = acc[i][1] = acc[i][2] = acc[i][3] = 0.f; }

    for (int k0 = 0; k0 < K; k0 += 32) {
        // stage A tile (64 x 32) transposed into sAT[k][row]
        {
            int gr = row0 + r;
            float4 v = {0.f, 0.f, 0.f, 0.f};
            if (gr < N_NODES) v = *(const float4*)(A + (size_t)gr * K + k0 + (q << 2));
            sAT[(q * 4 + 0) * 68 + r] = v.x;
            sAT[(q * 4 + 1) * 68 + r] = v.y;
            sAT[(q * 4 + 2) * 68 + r] = v.z;
            sAT[(q * 4 + 3) * 68 + r] = v.w;
            int gr2 = gr + 32;
            float4 v2 = {0.f, 0.f, 0.f, 0.f};
            if (gr2 < N_NODES) v2 = *(const float4*)(A + (size_t)gr2 * K + k0 + (q << 2));
            sAT[(q * 4 + 0) * 68 + r + 32] = v2.x;
            sAT[(q * 4 + 1) * 68 + r + 32] = v2.y;
            sAT[(q * 4 + 2) * 68 + r + 32] = v2.z;
            sAT[(q * 4 + 3) * 68 + r + 32] = v2.w;
        }
        // stage W tile (32 x 256) — contiguous in global
        {
            const float4* Wg = (const float4*)(W + (size_t)k0 * 256);
            float4* sWv = (float4*)sW;
#pragma unroll
            for (int i = 0; i < 8; ++i) sWv[t + (i << 8)] = Wg[t + (i << 8)];
        }
        __syncthreads();
#pragma unroll 4
        for (int kk = 0; kk < 32; ++kk) {
            float av[16];
            *(float4*)(av + 0)  = *(const float4*)(sAT + kk * 68 + r0 + 0);
            *(float4*)(av + 4)  = *(const float4*)(sAT + kk * 68 + r0 + 4);
            *(float4*)(av + 8)  = *(const float4*)(sAT + kk * 68 + r0 + 8);
            *(float4*)(av + 12) = *(const float4*)(sAT + kk * 68 + r0 + 12);
            float4 wv = *(const float4*)(sW + (kk << 8) + c4);
#pragma unroll
            for (int i = 0; i < 16; ++i) {
                acc[i][0] = fmaf(av[i], wv.x, acc[i][0]);
                acc[i][1] = fmaf(av[i], wv.y, acc[i][1]);
                acc[i][2] = fmaf(av[i], wv.z, acc[i][2]);
                acc[i][3] = fmaf(av[i], wv.w, acc[i][3]);
            }
        }
        __syncthreads();
    }
    // epilogue: bias + relu + store (+ BN partial stats)
    float4 bv = *(const float4*)(bias + c4);
    float s0 = 0, s1 = 0, s2 = 0, s3 = 0, q0 = 0, q1 = 0, q2 = 0, q3 = 0;
#pragma unroll
    for (int i = 0; i < 16; ++i) {
        int gr = row0 + r0 + i;
        if (gr < N_NODES) {
            float o0 = fmaxf(acc[i][0] + bv.x, 0.f);
            float o1 = fmaxf(acc[i][1] + bv.y, 0.f);
            float o2 = fmaxf(acc[i][2] + bv.z, 0.f);
            float o3 = fmaxf(acc[i][3] + bv.w, 0.f);
            float4 o = {o0, o1, o2, o3};
            *(float4*)(C + (size_t)gr * 256 + c4) = o;
            if (BN) {
                s0 += o0; s1 += o1; s2 += o2; s3 += o3;
                q0 += o0 * o0; q1 += o1 * o1; q2 += o2 * o2; q3 += o3 * o3;
            }
        }
    }
    if (BN) {
        atomicAdd(bnsum + c4 + 0, s0); atomicAdd(bnsumsq + c4 + 0, q0);
        atomicAdd(bnsum + c4 + 1, s1); atomicAdd(bnsumsq + c4 + 1, q1);
        atomicAdd(bnsum + c4 + 2, s2); atomicAdd(bnsumsq + c4 + 2, q2);
        atomicAdd(bnsum + c4 + 3, s3); atomicAdd(bnsumsq + c4 + 3, q3);
    }
}

// scale[c] = g[c]*rstd ; shift[c] = beta[c] - mu*g[c]*rstd
__global__ void bn_finalize_kernel(const float* __restrict__ sum, const float* __restrict__ sumsq,
                                   const float* __restrict__ g, const float* __restrict__ beta,
                                   float* __restrict__ scale, float* __restrict__ shift) {
    int c = threadIdx.x;
    float mu = sum[c] * (1.0f / N_NODES);
    float var = sumsq[c] * (1.0f / N_NODES) - mu * mu;
    float rstd = rsqrtf(var + 1e-5f);
    float sc = g[c] * rstd;
    scale[c] = sc;
    shift[c] = beta[c] - mu * sc;
}

__global__ __launch_bounds__(256)
void bn_apply_kernel(float* __restrict__ h, const float* __restrict__ scale,
                     const float* __restrict__ shift) {
    int tid = blockIdx.x * 256 + threadIdx.x;
    if (tid >= N_NODES * 64) return;
    int n = tid >> 6;
    int c = (tid & 63) << 2;
    float4 v = *(const float4*)(h + (size_t)n * 256 + c);
    float4 s = *(const float4*)(scale + c);
    float4 b = *(const float4*)(shift + c);
    v.x = v.x * s.x + b.x;
    v.y = v.y * s.y + b.y;
    v.z = v.z * s.z + b.z;
    v.w = v.w * s.w + b.w;
    *(float4*)(h + (size_t)n * 256 + c) = v;
}

__global__ void count_kernel(const int* __restrict__ batch, float* __restrict__ cnt) {
    int tid = blockIdx.x * 256 + threadIdx.x;
    if (tid < N_NODES) atomicAdd(&cnt[batch[tid]], 1.0f);
}

__global__ void rsqrt_kernel(float* __restrict__ cnt, int n) {
    int tid = blockIdx.x * 256 + threadIdx.x;
    if (tid < n) cnt[tid] = rsqrtf(fmaxf(cnt[tid], 1.0f));
}

__global__ __launch_bounds__(256)
void pool_kernel(const float* __restrict__ h, const int* __restrict__ batch,
                 const float* __restrict__ invs, float* __restrict__ out) {
    int tid = blockIdx.x * 256 + threadIdx.x;
    if (tid >= N_NODES * 64) return;
    int n = tid >> 6;
    int c = (tid & 63) << 2;
    int b = batch[n];
    float w = invs[b];
    float4 v = *(const float4*)(h + (size_t)n * 256 + c);
    float* p = out + (size_t)b * 256 + c;
    atomicAdd(p + 0, v.x * w);
    atomicAdd(p + 1, v.y * w);
    atomicAdd(p + 2, v.z * w);
    atomicAdd(p + 3, v.w * w);
}

// ---------------------------------------------------------------------------
extern "C" void kernel_launch(void* const* d_in, const int* in_sizes, int n_in,
                              void* d_out, int out_size, void* d_ws, size_t ws_size,
                              hipStream_t stream) {
    const float* x  = (const float*)d_in[0];
    const float* ea = (const float*)d_in[1];
    const int*   ei = (const int*)d_in[2];
    const int*   fb = (const int*)d_in[3];
    const int*   gb = (const int*)d_in[4];
    const float* W1[3]   = {(const float*)d_in[5],  (const float*)d_in[11], (const float*)d_in[17]};
    const float* B1[3]   = {(const float*)d_in[6],  (const float*)d_in[12], (const float*)d_in[18]};
    const float* W2[3]   = {(const float*)d_in[7],  (const float*)d_in[13], (const float*)d_in[19]};
    const float* B2[3]   = {(const float*)d_in[8],  (const float*)d_in[14], (const float*)d_in[20]};
    const float* G[3]    = {(const float*)d_in[9],  (const float*)d_in[15], (const float*)d_in[21]};
    const float* BETA[3] = {(const float*)d_in[10], (const float*)d_in[16], (const float*)d_in[22]};

    float* ws = (float*)d_ws;
    size_t off = 0;
    float* agg   = ws + off; off += (size_t)N_NODES * 288;   // max fin
    float* h1    = ws + off; off += (size_t)N_NODES * 256;
    float* xbuf  = ws + off; off += (size_t)N_NODES * 256;
    float* agg_e = ws + off; off += (size_t)N_NODES * DE;
    float* bn    = ws + off; off += 3 * 1024;                // per layer: sum|sumsq|scale|shift
    float* cnt_f = ws + off; off += N_FRAG;
    float* cnt_g = ws + off; off += N_GRAPH;

    // zero scratch that is accumulated into (ws/d_out are poisoned each call)
    hipMemsetAsync(agg_e, 0, (size_t)N_NODES * DE * sizeof(float), stream);
    hipMemsetAsync(bn, 0, (3 * 1024 + N_FRAG + N_GRAPH) * sizeof(float), stream);
    hipMemsetAsync(d_out, 0, (size_t)out_size * sizeof(float), stream);

    edge_agg_kernel<<<(N_EDGES * 8 + 255) / 256, 256, 0, stream>>>(ea, ei, agg_e);
    count_kernel<<<(N_NODES + 255) / 256, 256, 0, stream>>>(fb, cnt_f);
    count_kernel<<<(N_NODES + 255) / 256, 256, 0, stream>>>(gb, cnt_g);
    rsqrt_kernel<<<(N_FRAG + 255) / 256, 256, 0, stream>>>(cnt_f, N_FRAG);
    rsqrt_kernel<<<(N_GRAPH + 255) / 256, 256, 0, stream>>>(cnt_g, N_GRAPH);

    const int nblk_gemm = (N_NODES + 63) / 64;
    const float* xin = x;
    for (int l = 0; l < 3; ++l) {
        const int din = (l == 0) ? 128 : 256;
        const int fin = din + DE;
        const int shift = (din == 128) ? 5 : 6;
        float* bsum = bn + l * 1024;
        float* bsumsq = bsum + 256;
        float* bscale = bsum + 512;
        float* bshift = bsum + 768;

        init_agg_kernel<<<(N_NODES * (fin >> 2) + 255) / 256, 256, 0, stream>>>(xin, agg_e, agg, din, fin);
        scatter_kernel<<<(N_EDGES * (din >> 2) + 255) / 256, 256, 0, stream>>>(xin, ei, agg, din, fin, shift);
        gemm_relu_kernel<false><<<nblk_gemm, 256, 0, stream>>>(agg, W1[l], B1[l], h1, fin, nullptr, nullptr);
        gemm_relu_kernel<true><<<nblk_gemm, 256, 0, stream>>>(h1, W2[l], B2[l], xbuf, 256, bsum, bsumsq);
        bn_finalize_kernel<<<1, 256, 0, stream>>>(bsum, bsumsq, G[l], BETA[l], bscale, bshift);
        bn_apply_kernel<<<(N_NODES * 64 + 255) / 256, 256, 0, stream>>>(xbuf, bscale, bshift);
        xin = xbuf;
    }

    pool_kernel<<<(N_NODES * 64 + 255) / 256, 256, 0, stream>>>(xbuf, fb, cnt_f, (float*)d_out);
    pool_kernel<<<(N_NODES * 64 + 255) / 256, 256, 0, stream>>>(xbuf, gb, cnt_g, (float*)d_out + (size_t)N_FRAG * 256);
}

// Round 2
// 1196.435 us; speedup vs baseline: 3.1409x; 3.1409x over previous
//
#include <hip/hip_runtime.h>

#define N_NODES 50000
#define N_EDGES 200000
#define DE 32
#define N_FRAG 10000
#define N_GRAPH 2000

// ---------------------------------------------------------------------------
// CSR build: in-degree count, scan, fill
__global__ __launch_bounds__(256)
void count_deg_kernel(const int* __restrict__ ei, int* __restrict__ deg) {
    int e = blockIdx.x * 256 + threadIdx.x;
    if (e < N_EDGES) atomicAdd(&deg[ei[N_EDGES + e]], 1);
}

// exclusive scan of cnt[0..n) -> ptr[0..n]; single block of 1024 threads
__global__ __launch_bounds__(1024)
void scan_kernel(const int* __restrict__ cnt, int n, int* __restrict__ ptr) {
    __shared__ int part[1024];
    const int t = threadIdx.x;
    const int c = (n + 1023) / 1024;
    int beg = t * c;
    int end = min(beg + c, n);
    int s = 0;
    for (int i = beg; i < end; ++i) s += cnt[i];
    part[t] = s;
    __syncthreads();
    for (int off = 1; off < 1024; off <<= 1) {
        int v = part[t];
        int add = (t >= off) ? part[t - off] : 0;
        __syncthreads();
        part[t] = v + add;
        __syncthreads();
    }
    int pre = (t > 0) ? part[t - 1] : 0;
    for (int i = beg; i < end; ++i) { ptr[i] = pre; pre += cnt[i]; }
    if (t == 1023) ptr[n] = part[1023];
}

__global__ __launch_bounds__(256)
void fill_csr_kernel(const int* __restrict__ ei, const int* __restrict__ row_ptr,
                     int* __restrict__ fill, int* __restrict__ csr_src,
                     int* __restrict__ csr_eid) {
    int e = blockIdx.x * 256 + threadIdx.x;
    if (e >= N_EDGES) return;
    int dst = ei[N_EDGES + e];
    int pos = row_ptr[dst] + atomicAdd(&fill[dst], 1);
    csr_src[pos] = ei[e];
    csr_eid[pos] = e;
}

// ptr[s] = lower_bound(batch, s) for s in [0, nseg]; batch is sorted
__global__ __launch_bounds__(256)
void segptr_kernel(const int* __restrict__ batch, int nseg, int* __restrict__ ptr) {
    int s = blockIdx.x * 256 + threadIdx.x;
    if (s > nseg) return;
    int lo = 0, hi = N_NODES;
    while (lo < hi) {
        int mid = (lo + hi) >> 1;
        if (batch[mid] < s) lo = mid + 1; else hi = mid;
    }
    ptr[s] = lo;
}

// ---------------------------------------------------------------------------
// agg_e[n] = sum over incoming edges of relu(edge_attr[e])  [N,32]
// 8 threads per node (32 cols / 4), 32 nodes per block
__global__ __launch_bounds__(256)
void edge_gather_kernel(const float* __restrict__ ea, const int* __restrict__ row_ptr,
                        const int* __restrict__ csr_eid, float* __restrict__ agg_e) {
    int t = threadIdx.x;
    int g = t >> 3;
    int j = t & 7;
    int n = blockIdx.x * 32 + g;
    if (n >= N_NODES) return;
    int col = j << 2;
    float4 acc = {0.f, 0.f, 0.f, 0.f};
    int beg = row_ptr[n], end = row_ptr[n + 1];
    for (int e = beg; e < end; ++e) {
        int eid = csr_eid[e];
        float4 v = *(const float4*)(ea + (size_t)eid * DE + col);
        acc.x += fmaxf(v.x, 0.f);
        acc.y += fmaxf(v.y, 0.f);
        acc.z += fmaxf(v.z, 0.f);
        acc.w += fmaxf(v.w, 0.f);
    }
    *(float4*)(agg_e + (size_t)n * DE + col) = acc;
}

// agg[n][0:din] = x[n] + sum relu(x[src]);  agg[n][din:fin] = agg_e[n]
// gsize = din/4 threads per node
__global__ __launch_bounds__(256)
void gather_agg_kernel(const float* __restrict__ x, const int* __restrict__ row_ptr,
                       const int* __restrict__ csr_src, const float* __restrict__ agg_e,
                       float* __restrict__ agg, int din, int fin, int gsize_log2) {
    int t = threadIdx.x;
    int g = t >> gsize_log2;
    int j = t & ((1 << gsize_log2) - 1);
    int n = blockIdx.x * (256 >> gsize_log2) + g;
    if (n >= N_NODES) return;
    int col = j << 2;
    float4 acc = *(const float4*)(x + (size_t)n * din + col);  // self term (1+eps)*x, eps=0
    int beg = row_ptr[n], end = row_ptr[n + 1];
    for (int e = beg; e < end; ++e) {
        int src = csr_src[e];
        float4 v = *(const float4*)(x + (size_t)src * din + col);
        acc.x += fmaxf(v.x, 0.f);
        acc.y += fmaxf(v.y, 0.f);
        acc.z += fmaxf(v.z, 0.f);
        acc.w += fmaxf(v.w, 0.f);
    }
    *(float4*)(agg + (size_t)n * fin + col) = acc;
    if (j < 8) {   // edge-feature slice
        float4 v = *(const float4*)(agg_e + (size_t)n * DE + (j << 2));
        *(float4*)(agg + (size_t)n * fin + din + (j << 2)) = v;
    }
}

// ---------------------------------------------------------------------------
// C[r][c] = relu(A[r][:] @ W[:][c] + bias[c]);  A: N x K (stride K), W: K x 256.
// If BN: per-block LDS reduction of per-channel sum/sumsq, then global atomics.
template <bool BN>
__global__ __launch_bounds__(256)
void gemm_relu_kernel(const float* __restrict__ A, const float* __restrict__ W,
                      const float* __restrict__ bias, float* __restrict__ C,
                      int K, float* __restrict__ bnsum, float* __restrict__ bnsumsq) {
    __shared__ float sAT[32 * 68];   // [k][row], stride 68
    __shared__ float sW[32 * 256];   // [k][col]  (reused as BN reduction buffer)
    const int t = threadIdx.x;
    const int lane = t & 63;
    const int wave = t >> 6;
    const int r0 = wave << 4;
    const int c4 = lane << 2;
    const int row0 = blockIdx.x << 6;
    const int r = t >> 3;
    const int q = t & 7;

    float acc[16][4];
#pragma unroll
    for (int i = 0; i < 16; ++i) { acc[i][0] = acc[i][1] = acc[i][2] = acc[i][3] = 0.f; }

    for (int k0 = 0; k0 < K; k0 += 32) {
        {
            int gr = row0 + r;
            float4 v = {0.f, 0.f, 0.f, 0.f};
            if (gr < N_NODES) v = *(const float4*)(A + (size_t)gr * K + k0 + (q << 2));
            sAT[(q * 4 + 0) * 68 + r] = v.x;
            sAT[(q * 4 + 1) * 68 + r] = v.y;
            sAT[(q * 4 + 2) * 68 + r] = v.z;
            sAT[(q * 4 + 3) * 68 + r] = v.w;
            int gr2 = gr + 32;
            float4 v2 = {0.f, 0.f, 0.f, 0.f};
            if (gr2 < N_NODES) v2 = *(const float4*)(A + (size_t)gr2 * K + k0 + (q << 2));
            sAT[(q * 4 + 0) * 68 + r + 32] = v2.x;
            sAT[(q * 4 + 1) * 68 + r + 32] = v2.y;
            sAT[(q * 4 + 2) * 68 + r + 32] = v2.z;
            sAT[(q * 4 + 3) * 68 + r + 32] = v2.w;
        }
        {
            const float4* Wg = (const float4*)(W + (size_t)k0 * 256);
            float4* sWv = (float4*)sW;
#pragma unroll
            for (int i = 0; i < 8; ++i) sWv[t + (i << 8)] = Wg[t + (i << 8)];
        }
        __syncthreads();
#pragma unroll 4
        for (int kk = 0; kk < 32; ++kk) {
            float av[16];
            *(float4*)(av + 0)  = *(const float4*)(sAT + kk * 68 + r0 + 0);
            *(float4*)(av + 4)  = *(const float4*)(sAT + kk * 68 + r0 + 4);
            *(float4*)(av + 8)  = *(const float4*)(sAT + kk * 68 + r0 + 8);
            *(float4*)(av + 12) = *(const float4*)(sAT + kk * 68 + r0 + 12);
            float4 wv = *(const float4*)(sW + (kk << 8) + c4);
#pragma unroll
            for (int i = 0; i < 16; ++i) {
                acc[i][0] = fmaf(av[i], wv.x, acc[i][0]);
                acc[i][1] = fmaf(av[i], wv.y, acc[i][1]);
                acc[i][2] = fmaf(av[i], wv.z, acc[i][2]);
                acc[i][3] = fmaf(av[i], wv.w, acc[i][3]);
            }
        }
        __syncthreads();
    }
    float4 bv = *(const float4*)(bias + c4);
    float s0 = 0, s1 = 0, s2 = 0, s3 = 0, q0 = 0, q1 = 0, q2 = 0, q3 = 0;
#pragma unroll
    for (int i = 0; i < 16; ++i) {
        int gr = row0 + r0 + i;
        if (gr < N_NODES) {
            float o0 = fmaxf(acc[i][0] + bv.x, 0.f);
            float o1 = fmaxf(acc[i][1] + bv.y, 0.f);
            float o2 = fmaxf(acc[i][2] + bv.z, 0.f);
            float o3 = fmaxf(acc[i][3] + bv.w, 0.f);
            float4 o = {o0, o1, o2, o3};
            *(float4*)(C + (size_t)gr * 256 + c4) = o;
            if (BN) {
                s0 += o0; s1 += o1; s2 += o2; s3 += o3;
                q0 += o0 * o0; q1 += o1 * o1; q2 += o2 * o2; q3 += o3 * o3;
            }
        }
    }
    if (BN) {
        // per-block reduction in LDS (reuse sW; all waves are past the last barrier)
        float* red = sW;           // need 4 waves * 512 floats = 2048 <= 8192
        float* myred = red + (wave << 9);
        myred[c4 + 0] = s0; myred[c4 + 1] = s1; myred[c4 + 2] = s2; myred[c4 + 3] = s3;
        myred[256 + c4 + 0] = q0; myred[256 + c4 + 1] = q1;
        myred[256 + c4 + 2] = q2; myred[256 + c4 + 3] = q3;
        __syncthreads();
        if (wave == 0) {
#pragma unroll
            for (int k = 0; k < 4; ++k) {
                float vs = red[c4 + k]       + red[512 + c4 + k]
                         + red[1024 + c4 + k] + red[1536 + c4 + k];
                float vq = red[256 + c4 + k]  + red[768 + c4 + k]
                         + red[1280 + c4 + k] + red[1792 + c4 + k];
                atomicAdd(bnsum + c4 + k, vs);
                atomicAdd(bnsumsq + c4 + k, vq);
            }
        }
    }
}

__global__ void bn_finalize_kernel(const float* __restrict__ sum, const float* __restrict__ sumsq,
                                   const float* __restrict__ g, const float* __restrict__ beta,
                                   float* __restrict__ scale, float* __restrict__ shift) {
    int c = threadIdx.x;
    float mu = sum[c] * (1.0f / N_NODES);
    float var = sumsq[c] * (1.0f / N_NODES) - mu * mu;
    float rstd = rsqrtf(var + 1e-5f);
    float sc = g[c] * rstd;
    scale[c] = sc;
    shift[c] = beta[c] - mu * sc;
}

__global__ __launch_bounds__(256)
void bn_apply_kernel(float* __restrict__ h, const float* __restrict__ scale,
                     const float* __restrict__ shift) {
    int tid = blockIdx.x * 256 + threadIdx.x;
    if (tid >= N_NODES * 64) return;
    int n = tid >> 6;
    int c = (tid & 63) << 2;
    float4 v = *(const float4*)(h + (size_t)n * 256 + c);
    float4 s = *(const float4*)(scale + c);
    float4 b = *(const float4*)(shift + c);
    v.x = v.x * s.x + b.x;
    v.y = v.y * s.y + b.y;
    v.z = v.z * s.z + b.z;
    v.w = v.w * s.w + b.w;
    *(float4*)(h + (size_t)n * 256 + c) = v;
}

// segmented sqrt-pool: segment s covers node rows [ptr[s], ptr[s+1])
// 64 threads per segment, 4 segments per block; no atomics
__global__ __launch_bounds__(256)
void pool_seg_kernel(const float* __restrict__ h, const int* __restrict__ ptr,
                     float* __restrict__ out, int nseg) {
    int t = threadIdx.x;
    int g = t >> 6;
    int j = t & 63;
    int s = blockIdx.x * 4 + g;
    if (s >= nseg) return;
    int beg = ptr[s], end = ptr[s + 1];
    int col = j << 2;
    float4 acc = {0.f, 0.f, 0.f, 0.f};
    for (int i = beg; i < end; ++i) {
        float4 v = *(const float4*)(h + (size_t)i * 256 + col);
        acc.x += v.x; acc.y += v.y; acc.z += v.z; acc.w += v.w;
    }
    float w = rsqrtf(fmaxf((float)(end - beg), 1.0f));
    float4 o = {acc.x * w, acc.y * w, acc.z * w, acc.w * w};
    *(float4*)(out + (size_t)s * 256 + col) = o;
}

// ---------------------------------------------------------------------------
extern "C" void kernel_launch(void* const* d_in, const int* in_sizes, int n_in,
                              void* d_out, int out_size, void* d_ws, size_t ws_size,
                              hipStream_t stream) {
    const float* x  = (const float*)d_in[0];
    const float* ea = (const float*)d_in[1];
    const int*   ei = (const int*)d_in[2];
    const int*   fb = (const int*)d_in[3];
    const int*   gb = (const int*)d_in[4];
    const float* W1[3]   = {(const float*)d_in[5],  (const float*)d_in[11], (const float*)d_in[17]};
    const float* B1[3]   = {(const float*)d_in[6],  (const float*)d_in[12], (const float*)d_in[18]};
    const float* W2[3]   = {(const float*)d_in[7],  (const float*)d_in[13], (const float*)d_in[19]};
    const float* B2[3]   = {(const float*)d_in[8],  (const float*)d_in[14], (const float*)d_in[20]};
    const float* G[3]    = {(const float*)d_in[9],  (const float*)d_in[15], (const float*)d_in[21]};
    const float* BETA[3] = {(const float*)d_in[10], (const float*)d_in[16], (const float*)d_in[22]};

    float* ws = (float*)d_ws;
    size_t off = 0;
    float* agg   = ws + off; off += (size_t)N_NODES * 288;   // max fin
    float* h1    = ws + off; off += (size_t)N_NODES * 256;
    float* xbuf  = ws + off; off += (size_t)N_NODES * 256;
    float* agg_e = ws + off; off += (size_t)N_NODES * DE;
    float* bn    = ws + off; off += 3 * 1024;                // per layer: sum|sumsq|scale|shift
    int* iw      = (int*)(ws + off);
    int* row_ptr = iw;                     iw += N_NODES + 1;
    int* deg     = iw;                     iw += N_NODES;
    int* fill    = iw;                     iw += N_NODES;
    int* csr_src = iw;                     iw += N_EDGES;
    int* csr_eid = iw;                     iw += N_EDGES;
    int* frag_ptr = iw;                    iw += N_FRAG + 1;
    int* graph_ptr = iw;                   iw += N_GRAPH + 1;

    // zero only what is accumulated into (deg+fill contiguous, bn stats)
    hipMemsetAsync(deg, 0, 2 * N_NODES * sizeof(int), stream);
    hipMemsetAsync(bn, 0, 3 * 1024 * sizeof(float), stream);

    // CSR build
    count_deg_kernel<<<(N_EDGES + 255) / 256, 256, 0, stream>>>(ei, deg);
    scan_kernel<<<1, 1024, 0, stream>>>(deg, N_NODES, row_ptr);
    fill_csr_kernel<<<(N_EDGES + 255) / 256, 256, 0, stream>>>(ei, row_ptr, fill, csr_src, csr_eid);

    // segment pointers for pooling (batch arrays are sorted)
    segptr_kernel<<<(N_FRAG + 1 + 255) / 256, 256, 0, stream>>>(fb, N_FRAG, frag_ptr);
    segptr_kernel<<<(N_GRAPH + 1 + 255) / 256, 256, 0, stream>>>(gb, N_GRAPH, graph_ptr);

    // edge-feature aggregation (shared by all 3 layers)
    edge_gather_kernel<<<(N_NODES + 31) / 32, 256, 0, stream>>>(ea, row_ptr, csr_eid, agg_e);

    const int nblk_gemm = (N_NODES + 63) / 64;
    const float* xin = x;
    for (int l = 0; l < 3; ++l) {
        const int din = (l == 0) ? 128 : 256;
        const int fin = din + DE;
        const int gl2 = (din == 128) ? 5 : 6;       // log2(din/4)
        const int npb = 256 >> gl2;                  // nodes per block
        float* bsum = bn + l * 1024;
        float* bsumsq = bsum + 256;
        float* bscale = bsum + 512;
        float* bshift = bsum + 768;

        gather_agg_kernel<<<(N_NODES + npb - 1) / npb, 256, 0, stream>>>(
            xin, row_ptr, csr_src, agg_e, agg, din, fin, gl2);
        gemm_relu_kernel<false><<<nblk_gemm, 256, 0, stream>>>(agg, W1[l], B1[l], h1, fin, nullptr, nullptr);
        gemm_relu_kernel<true><<<nblk_gemm, 256, 0, stream>>>(h1, W2[l], B2[l], xbuf, 256, bsum, bsumsq);
        bn_finalize_kernel<<<1, 256, 0, stream>>>(bsum, bsumsq, G[l], BETA[l], bscale, bshift);
        bn_apply_kernel<<<(N_NODES * 64 + 255) / 256, 256, 0, stream>>>(xbuf, bscale, bshift);
        xin = xbuf;
    }

    pool_seg_kernel<<<(N_FRAG + 3) / 4, 256, 0, stream>>>(xbuf, frag_ptr, (float*)d_out, N_FRAG);
    pool_seg_kernel<<<(N_GRAPH + 3) / 4, 256, 0, stream>>>(xbuf, graph_ptr,
                                                           (float*)d_out + (size_t)N_FRAG * 256, N_GRAPH);
}

// Round 4
// 728.258 us; speedup vs baseline: 5.1601x; 1.6429x over previous
//
#include <hip/hip_runtime.h>

#define N_NODES 50000
#define N_EDGES 200000
#define DE 32
#define N_FRAG 10000
#define N_GRAPH 2000

typedef __attribute__((ext_vector_type(8))) short short8;
typedef __attribute__((ext_vector_type(4))) float f32x4;

__device__ __forceinline__ unsigned short f2bf(float f) {
    unsigned u = __float_as_uint(f);
    u += 0x7FFF + ((u >> 16) & 1);      // RNE (no NaN inputs here)
    return (unsigned short)(u >> 16);
}

// split x = hi + lo (hi=bf16(x), lo=bf16(x-hi)); x-hi exact in fp32
__device__ __forceinline__ void split2(float f, unsigned short& h, unsigned short& l) {
    h = f2bf(f);
    float fh = __uint_as_float((unsigned)h << 16);
    l = f2bf(f - fh);
}

// ---------------------------------------------------------------------------
// CSR build: in-degree count, scan, fill
__global__ __launch_bounds__(256)
void count_deg_kernel(const int* __restrict__ ei, int* __restrict__ deg) {
    int e = blockIdx.x * 256 + threadIdx.x;
    if (e < N_EDGES) atomicAdd(&deg[ei[N_EDGES + e]], 1);
}

__global__ __launch_bounds__(1024)
void scan_kernel(const int* __restrict__ cnt, int n, int* __restrict__ ptr) {
    __shared__ int part[1024];
    const int t = threadIdx.x;
    const int c = (n + 1023) / 1024;
    int beg = t * c;
    int end = min(beg + c, n);
    int s = 0;
    for (int i = beg; i < end; ++i) s += cnt[i];
    part[t] = s;
    __syncthreads();
    for (int off = 1; off < 1024; off <<= 1) {
        int v = part[t];
        int add = (t >= off) ? part[t - off] : 0;
        __syncthreads();
        part[t] = v + add;
        __syncthreads();
    }
    int pre = (t > 0) ? part[t - 1] : 0;
    for (int i = beg; i < end; ++i) { ptr[i] = pre; pre += cnt[i]; }
    if (t == 1023) ptr[n] = part[1023];
}

__global__ __launch_bounds__(256)
void fill_csr_kernel(const int* __restrict__ ei, const int* __restrict__ row_ptr,
                     int* __restrict__ fill, int* __restrict__ csr_src,
                     int* __restrict__ csr_eid) {
    int e = blockIdx.x * 256 + threadIdx.x;
    if (e >= N_EDGES) return;
    int dst = ei[N_EDGES + e];
    int pos = row_ptr[dst] + atomicAdd(&fill[dst], 1);
    csr_src[pos] = ei[e];
    csr_eid[pos] = e;
}

__global__ __launch_bounds__(256)
void segptr_kernel(const int* __restrict__ batch, int nseg, int* __restrict__ ptr) {
    int s = blockIdx.x * 256 + threadIdx.x;
    if (s > nseg) return;
    int lo = 0, hi = N_NODES;
    while (lo < hi) {
        int mid = (lo + hi) >> 1;
        if (batch[mid] < s) lo = mid + 1; else hi = mid;
    }
    ptr[s] = lo;
}

// ---------------------------------------------------------------------------
// W [K][256] fp32  ->  WThi/WTlo [256][K] bf16 split
__global__ __launch_bounds__(256)
void wt_kernel(const float* __restrict__ W, unsigned short* __restrict__ WThi,
               unsigned short* __restrict__ WTlo, int K) {
    int id = blockIdx.x * 256 + threadIdx.x;
    if (id >= K * 256) return;
    int c = id / K, k = id - c * K;
    unsigned short h, l;
    split2(W[(size_t)k * 256 + c], h, l);
    WThi[id] = h;
    WTlo[id] = l;
}

// ---------------------------------------------------------------------------
// agg_e[n] = sum over incoming edges of relu(edge_attr[e])  [N,32]
__global__ __launch_bounds__(256)
void edge_gather_kernel(const float* __restrict__ ea, const int* __restrict__ row_ptr,
                        const int* __restrict__ csr_eid, float* __restrict__ agg_e) {
    int t = threadIdx.x;
    int g = t >> 3;
    int j = t & 7;
    int n = blockIdx.x * 32 + g;
    if (n >= N_NODES) return;
    int col = j << 2;
    float4 acc = {0.f, 0.f, 0.f, 0.f};
    int beg = row_ptr[n], end = row_ptr[n + 1];
    for (int e = beg; e < end; ++e) {
        int eid = csr_eid[e];
        float4 v = *(const float4*)(ea + (size_t)eid * DE + col);
        acc.x += fmaxf(v.x, 0.f);
        acc.y += fmaxf(v.y, 0.f);
        acc.z += fmaxf(v.z, 0.f);
        acc.w += fmaxf(v.w, 0.f);
    }
    *(float4*)(agg_e + (size_t)n * DE + col) = acc;
}

// agg[n][0:din] = x[n] + sum relu(x[src]);  agg[n][din:fin] = agg_e[n]
__global__ __launch_bounds__(256)
void gather_agg_kernel(const float* __restrict__ x, const int* __restrict__ row_ptr,
                       const int* __restrict__ csr_src, const float* __restrict__ agg_e,
                       float* __restrict__ agg, int din, int fin, int gsize_log2) {
    int t = threadIdx.x;
    int g = t >> gsize_log2;
    int j = t & ((1 << gsize_log2) - 1);
    int n = blockIdx.x * (256 >> gsize_log2) + g;
    if (n >= N_NODES) return;
    int col = j << 2;
    float4 acc = *(const float4*)(x + (size_t)n * din + col);  // self term
    int beg = row_ptr[n], end = row_ptr[n + 1];
    for (int e = beg; e < end; ++e) {
        int src = csr_src[e];
        float4 v = *(const float4*)(x + (size_t)src * din + col);
        acc.x += fmaxf(v.x, 0.f);
        acc.y += fmaxf(v.y, 0.f);
        acc.z += fmaxf(v.z, 0.f);
        acc.w += fmaxf(v.w, 0.f);
    }
    *(float4*)(agg + (size_t)n * fin + col) = acc;
    if (j < 8) {
        float4 v = *(const float4*)(agg_e + (size_t)n * DE + (j << 2));
        *(float4*)(agg + (size_t)n * fin + din + (j << 2)) = v;
    }
}

// ---------------------------------------------------------------------------
// Split-bf16 MFMA GEMM: C = relu(A @ W + bias), fp32-equivalent accuracy via
// Ahi*Whi + Ahi*Wlo + Alo*Whi (lo*lo dropped).
// Block: 256 thr (4 waves), tile 64 rows x 256 cols, BK=32.
template <bool BN>
__global__ __launch_bounds__(256)
void gemm_mfma_kernel(const float* __restrict__ A, const unsigned short* __restrict__ WThi,
                      const unsigned short* __restrict__ WTlo,
                      const float* __restrict__ bias, float* __restrict__ C, int K,
                      float* __restrict__ bnsum) {
    __shared__ __align__(16) unsigned short sAhi[64 * 40];
    __shared__ __align__(16) unsigned short sAlo[64 * 40];
    __shared__ __align__(16) unsigned short sBhi[256 * 40];
    __shared__ __align__(16) unsigned short sBlo[256 * 40];
    const int t = threadIdx.x;
    const int l = t & 63;
    const int w = t >> 6;
    const int lr = l & 15;     // MFMA row/col within tile
    const int lq = l >> 4;     // quad
    const int row0 = blockIdx.x << 6;
    const int cb = w << 6;     // wave col base
    const int ar = t >> 2;     // A-staging row 0..63
    const int ac = t & 3;      // A-staging k-chunk 0..3

    f32x4 acc[4][4];
#pragma unroll
    for (int mt = 0; mt < 4; ++mt)
#pragma unroll
        for (int nt = 0; nt < 4; ++nt) acc[mt][nt] = (f32x4){0.f, 0.f, 0.f, 0.f};

    for (int k0 = 0; k0 < K; k0 += 32) {
        // stage A (64x32 fp32 -> hi/lo bf16)
        {
            float4 a0 = {0.f, 0.f, 0.f, 0.f}, a1 = {0.f, 0.f, 0.f, 0.f};
            int gr = row0 + ar;
            if (gr < N_NODES) {
                const float* ap = A + (size_t)gr * K + k0 + (ac << 3);
                a0 = *(const float4*)ap;
                a1 = *(const float4*)(ap + 4);
            }
            short8 hv, lv;
            unsigned short h, lo_;
            split2(a0.x, h, lo_); hv[0] = (short)h; lv[0] = (short)lo_;
            split2(a0.y, h, lo_); hv[1] = (short)h; lv[1] = (short)lo_;
            split2(a0.z, h, lo_); hv[2] = (short)h; lv[2] = (short)lo_;
            split2(a0.w, h, lo_); hv[3] = (short)h; lv[3] = (short)lo_;
            split2(a1.x, h, lo_); hv[4] = (short)h; lv[4] = (short)lo_;
            split2(a1.y, h, lo_); hv[5] = (short)h; lv[5] = (short)lo_;
            split2(a1.z, h, lo_); hv[6] = (short)h; lv[6] = (short)lo_;
            split2(a1.w, h, lo_); hv[7] = (short)h; lv[7] = (short)lo_;
            *(short8*)&sAhi[ar * 40 + (ac << 3)] = hv;
            *(short8*)&sAlo[ar * 40 + (ac << 3)] = lv;
        }
        // stage B (256 cols x 32 k, hi+lo pure copies)
#pragma unroll
        for (int i = 0; i < 4; ++i) {
            int c = t + (i << 8);
            int col = c >> 2, kc = c & 3;
            size_t goff = (size_t)col * K + k0 + (kc << 3);
            int soff = col * 40 + (kc << 3);
            *(short8*)&sBhi[soff] = *(const short8*)(WThi + goff);
            *(short8*)&sBlo[soff] = *(const short8*)(WTlo + goff);
        }
        __syncthreads();
        short8 afh[4], afl[4], bfh[4], bfl[4];
#pragma unroll
        for (int mt = 0; mt < 4; ++mt) {
            int soff = (mt * 16 + lr) * 40 + (lq << 3);
            afh[mt] = *(const short8*)&sAhi[soff];
            afl[mt] = *(const short8*)&sAlo[soff];
        }
#pragma unroll
        for (int nt = 0; nt < 4; ++nt) {
            int soff = (cb + nt * 16 + lr) * 40 + (lq << 3);
            bfh[nt] = *(const short8*)&sBhi[soff];
            bfl[nt] = *(const short8*)&sBlo[soff];
        }
#pragma unroll
        for (int mt = 0; mt < 4; ++mt)
#pragma unroll
            for (int nt = 0; nt < 4; ++nt) {
                acc[mt][nt] = __builtin_amdgcn_mfma_f32_16x16x32_bf16(
                    afl[mt], bfh[nt], acc[mt][nt], 0, 0, 0);
                acc[mt][nt] = __builtin_amdgcn_mfma_f32_16x16x32_bf16(
                    afh[mt], bfl[nt], acc[mt][nt], 0, 0, 0);
                acc[mt][nt] = __builtin_amdgcn_mfma_f32_16x16x32_bf16(
                    afh[mt], bfh[nt], acc[mt][nt], 0, 0, 0);
            }
        __syncthreads();
    }

    // epilogue: bias + relu + store (+BN stats)
    float b4[4];
#pragma unroll
    for (int nt = 0; nt < 4; ++nt) b4[nt] = bias[cb + nt * 16 + lr];
    float s4[4] = {0.f, 0.f, 0.f, 0.f}, q4[4] = {0.f, 0.f, 0.f, 0.f};
#pragma unroll
    for (int mt = 0; mt < 4; ++mt) {
#pragma unroll
        for (int i = 0; i < 4; ++i) {
            int row = row0 + mt * 16 + lq * 4 + i;   // C/D: row = quad*4 + reg
            if (row < N_NODES) {
                float* cp = C + (size_t)row * 256 + cb + lr;
#pragma unroll
                for (int nt = 0; nt < 4; ++nt) {
                    float o = fmaxf(acc[mt][nt][i] + b4[nt], 0.f);
                    cp[nt * 16] = o;
                    if (BN) { s4[nt] += o; q4[nt] += o * o; }
                }
            }
        }
    }
    if (BN) {
#pragma unroll
        for (int nt = 0; nt < 4; ++nt) {
            s4[nt] += __shfl_xor(s4[nt], 16); s4[nt] += __shfl_xor(s4[nt], 32);
            q4[nt] += __shfl_xor(q4[nt], 16); q4[nt] += __shfl_xor(q4[nt], 32);
        }
        float* sRed = (float*)sAhi;
        __syncthreads();
        if (lq == 0) {
#pragma unroll
            for (int nt = 0; nt < 4; ++nt) {
                int col = cb + nt * 16 + lr;
                sRed[col] = s4[nt];
                sRed[256 + col] = q4[nt];
            }
        }
        __syncthreads();
        atomicAdd(&bnsum[t], sRed[t]);
        atomicAdd(&bnsum[t + 256], sRed[t + 256]);
    }
}

__global__ void bn_finalize_kernel(const float* __restrict__ sum, const float* __restrict__ sumsq,
                                   const float* __restrict__ g, const float* __restrict__ beta,
                                   float* __restrict__ scale, float* __restrict__ shift) {
    int c = threadIdx.x;
    float mu = sum[c] * (1.0f / N_NODES);
    float var = sumsq[c] * (1.0f / N_NODES) - mu * mu;
    float rstd = rsqrtf(var + 1e-5f);
    float sc = g[c] * rstd;
    scale[c] = sc;
    shift[c] = beta[c] - mu * sc;
}

__global__ __launch_bounds__(256)
void bn_apply_kernel(float* __restrict__ h, const float* __restrict__ scale,
                     const float* __restrict__ shift) {
    int tid = blockIdx.x * 256 + threadIdx.x;
    if (tid >= N_NODES * 64) return;
    int n = tid >> 6;
    int c = (tid & 63) << 2;
    float4 v = *(const float4*)(h + (size_t)n * 256 + c);
    float4 s = *(const float4*)(scale + c);
    float4 b = *(const float4*)(shift + c);
    v.x = v.x * s.x + b.x;
    v.y = v.y * s.y + b.y;
    v.z = v.z * s.z + b.z;
    v.w = v.w * s.w + b.w;
    *(float4*)(h + (size_t)n * 256 + c) = v;
}

// segmented sqrt-pool, no atomics
__global__ __launch_bounds__(256)
void pool_seg_kernel(const float* __restrict__ h, const int* __restrict__ ptr,
                     float* __restrict__ out, int nseg) {
    int t = threadIdx.x;
    int g = t >> 6;
    int j = t & 63;
    int s = blockIdx.x * 4 + g;
    if (s >= nseg) return;
    int beg = ptr[s], end = ptr[s + 1];
    int col = j << 2;
    float4 acc = {0.f, 0.f, 0.f, 0.f};
    for (int i = beg; i < end; ++i) {
        float4 v = *(const float4*)(h + (size_t)i * 256 + col);
        acc.x += v.x; acc.y += v.y; acc.z += v.z; acc.w += v.w;
    }
    float w = rsqrtf(fmaxf((float)(end - beg), 1.0f));
    float4 o = {acc.x * w, acc.y * w, acc.z * w, acc.w * w};
    *(float4*)(out + (size_t)s * 256 + col) = o;
}

// ---------------------------------------------------------------------------
extern "C" void kernel_launch(void* const* d_in, const int* in_sizes, int n_in,
                              void* d_out, int out_size, void* d_ws, size_t ws_size,
                              hipStream_t stream) {
    const float* x  = (const float*)d_in[0];
    const float* ea = (const float*)d_in[1];
    const int*   ei = (const int*)d_in[2];
    const int*   fb = (const int*)d_in[3];
    const int*   gb = (const int*)d_in[4];
    const float* W1[3]   = {(const float*)d_in[5],  (const float*)d_in[11], (const float*)d_in[17]};
    const float* B1[3]   = {(const float*)d_in[6],  (const float*)d_in[12], (const float*)d_in[18]};
    const float* W2[3]   = {(const float*)d_in[7],  (const float*)d_in[13], (const float*)d_in[19]};
    const float* B2[3]   = {(const float*)d_in[8],  (const float*)d_in[14], (const float*)d_in[20]};
    const float* G[3]    = {(const float*)d_in[9],  (const float*)d_in[15], (const float*)d_in[21]};
    const float* BETA[3] = {(const float*)d_in[10], (const float*)d_in[16], (const float*)d_in[22]};

    const int FIN[3] = {160, 288, 288};

    float* ws = (float*)d_ws;
    size_t off = 0;
    float* agg   = ws + off; off += (size_t)N_NODES * 288;
    float* h1    = ws + off; off += (size_t)N_NODES * 256;
    float* xbuf  = ws + off; off += (size_t)N_NODES * 256;
    float* agg_e = ws + off; off += (size_t)N_NODES * DE;
    float* bn    = ws + off; off += 3 * 1024;
    unsigned short* w1hi[3]; unsigned short* w1lo[3];
    unsigned short* w2hi[3]; unsigned short* w2lo[3];
    {
        unsigned short* sw = (unsigned short*)(ws + off);
        unsigned short* sw0 = sw;
        for (int l = 0; l < 3; ++l) {
            w1hi[l] = sw; sw += 256 * FIN[l];
            w1lo[l] = sw; sw += 256 * FIN[l];
        }
        for (int l = 0; l < 3; ++l) {
            w2hi[l] = sw; sw += 256 * 256;
            w2lo[l] = sw; sw += 256 * 256;
        }
        off += (size_t)(sw - sw0 + 1) / 2;
    }
    int* iw      = (int*)(ws + off);
    int* row_ptr = iw;                     iw += N_NODES + 1;
    int* deg     = iw;                     iw += N_NODES;
    int* fill    = iw;                     iw += N_NODES;
    int* csr_src = iw;                     iw += N_EDGES;
    int* csr_eid = iw;                     iw += N_EDGES;
    int* frag_ptr = iw;                    iw += N_FRAG + 1;
    int* graph_ptr = iw;                   iw += N_GRAPH + 1;

    hipMemsetAsync(deg, 0, 2 * N_NODES * sizeof(int), stream);
    hipMemsetAsync(bn, 0, 3 * 1024 * sizeof(float), stream);

    // weight transpose + bf16 hi/lo split (once per layer)
    for (int l = 0; l < 3; ++l) {
        wt_kernel<<<(FIN[l] * 256 + 255) / 256, 256, 0, stream>>>(W1[l], w1hi[l], w1lo[l], FIN[l]);
        wt_kernel<<<(256 * 256 + 255) / 256, 256, 0, stream>>>(W2[l], w2hi[l], w2lo[l], 256);
    }

    // CSR build
    count_deg_kernel<<<(N_EDGES + 255) / 256, 256, 0, stream>>>(ei, deg);
    scan_kernel<<<1, 1024, 0, stream>>>(deg, N_NODES, row_ptr);
    fill_csr_kernel<<<(N_EDGES + 255) / 256, 256, 0, stream>>>(ei, row_ptr, fill, csr_src, csr_eid);

    segptr_kernel<<<(N_FRAG + 1 + 255) / 256, 256, 0, stream>>>(fb, N_FRAG, frag_ptr);
    segptr_kernel<<<(N_GRAPH + 1 + 255) / 256, 256, 0, stream>>>(gb, N_GRAPH, graph_ptr);

    edge_gather_kernel<<<(N_NODES + 31) / 32, 256, 0, stream>>>(ea, row_ptr, csr_eid, agg_e);

    const int nblk_gemm = (N_NODES + 63) / 64;
    const float* xin = x;
    for (int l = 0; l < 3; ++l) {
        const int din = (l == 0) ? 128 : 256;
        const int fin = FIN[l];
        const int gl2 = (din == 128) ? 5 : 6;
        const int npb = 256 >> gl2;
        float* bsum = bn + l * 1024;
        float* bscale = bsum + 512;
        float* bshift = bsum + 768;

        gather_agg_kernel<<<(N_NODES + npb - 1) / npb, 256, 0, stream>>>(
            xin, row_ptr, csr_src, agg_e, agg, din, fin, gl2);
        gemm_mfma_kernel<false><<<nblk_gemm, 256, 0, stream>>>(
            agg, w1hi[l], w1lo[l], B1[l], h1, fin, nullptr);
        gemm_mfma_kernel<true><<<nblk_gemm, 256, 0, stream>>>(
            h1, w2hi[l], w2lo[l], B2[l], xbuf, 256, bsum);
        bn_finalize_kernel<<<1, 256, 0, stream>>>(bsum, bsum + 256, G[l], BETA[l], bscale, bshift);
        bn_apply_kernel<<<(N_NODES * 64 + 255) / 256, 256, 0, stream>>>(xbuf, bscale, bshift);
        xin = xbuf;
    }

    pool_seg_kernel<<<(N_FRAG + 3) / 4, 256, 0, stream>>>(xbuf, frag_ptr, (float*)d_out, N_FRAG);
    pool_seg_kernel<<<(N_GRAPH + 3) / 4, 256, 0, stream>>>(xbuf, graph_ptr,
                                                           (float*)d_out + (size_t)N_FRAG * 256, N_GRAPH);
}

// Round 5
// 610.325 us; speedup vs baseline: 6.1572x; 1.1932x over previous
//
#include <hip/hip_runtime.h>

#define N_NODES 50000
#define N_EDGES 200000
#define DE 32
#define N_FRAG 10000
#define N_GRAPH 2000

typedef __attribute__((ext_vector_type(8))) short short8;
typedef __attribute__((ext_vector_type(4))) float f32x4;

__device__ __forceinline__ unsigned short f2bf(float f) {
    unsigned u = __float_as_uint(f);
    u += 0x7FFF + ((u >> 16) & 1);      // RNE (no NaN inputs here)
    return (unsigned short)(u >> 16);
}

// split x = hi + lo (hi=bf16(x), lo=bf16(x-hi)); x-hi exact in fp32
__device__ __forceinline__ void split2(float f, unsigned short& h, unsigned short& l) {
    h = f2bf(f);
    float fh = __uint_as_float((unsigned)h << 16);
    l = f2bf(f - fh);
}

// ---------------------------------------------------------------------------
// CSR build: in-degree count, hierarchical scan, fill
__global__ __launch_bounds__(256)
void count_deg_kernel(const int* __restrict__ ei, int* __restrict__ deg) {
    int e = blockIdx.x * 256 + threadIdx.x;
    if (e < N_EDGES) atomicAdd(&deg[ei[N_EDGES + e]], 1);
}

// per-block sum of 256 ints
__global__ __launch_bounds__(256)
void block_sum_kernel(const int* __restrict__ deg, int* __restrict__ bsum) {
    int i = blockIdx.x * 256 + threadIdx.x;
    int v = (i < N_NODES) ? deg[i] : 0;
#pragma unroll
    for (int o = 1; o < 64; o <<= 1) v += __shfl_xor(v, o);
    __shared__ int wsum[4];
    if ((threadIdx.x & 63) == 0) wsum[threadIdx.x >> 6] = v;
    __syncthreads();
    if (threadIdx.x == 0) bsum[blockIdx.x] = wsum[0] + wsum[1] + wsum[2] + wsum[3];
}

// exclusive scan of bsum[0..nb) in place (nb <= 256); 1 block
__global__ __launch_bounds__(256)
void top_scan_kernel(int* __restrict__ bsum, int nb) {
    __shared__ int s[256];
    int t = threadIdx.x;
    s[t] = (t < nb) ? bsum[t] : 0;
    __syncthreads();
    for (int o = 1; o < 256; o <<= 1) {
        int v = s[t];
        int a = (t >= o) ? s[t - o] : 0;
        __syncthreads();
        s[t] = v + a;
        __syncthreads();
    }
    if (t < nb) bsum[t] = (t > 0) ? s[t - 1] : 0;
}

// block-local exclusive scan + block offset -> row_ptr
__global__ __launch_bounds__(256)
void final_scan_kernel(const int* __restrict__ deg, const int* __restrict__ bsum,
                       int* __restrict__ ptr) {
    __shared__ int s[256];
    int i = blockIdx.x * 256 + threadIdx.x;
    int t = threadIdx.x;
    int v = (i < N_NODES) ? deg[i] : 0;
    s[t] = v;
    __syncthreads();
    for (int o = 1; o < 256; o <<= 1) {
        int x = s[t];
        int a = (t >= o) ? s[t - o] : 0;
        __syncthreads();
        s[t] = x + a;
        __syncthreads();
    }
    int incl = s[t];
    int base = bsum[blockIdx.x];
    if (i < N_NODES) ptr[i] = base + incl - v;
    if (i == N_NODES - 1) ptr[N_NODES] = base + incl;
}

__global__ __launch_bounds__(256)
void fill_csr_kernel(const int* __restrict__ ei, const int* __restrict__ row_ptr,
                     int* __restrict__ fill, int* __restrict__ csr_src,
                     int* __restrict__ csr_eid) {
    int e = blockIdx.x * 256 + threadIdx.x;
    if (e >= N_EDGES) return;
    int dst = ei[N_EDGES + e];
    int pos = row_ptr[dst] + atomicAdd(&fill[dst], 1);
    csr_src[pos] = ei[e];
    csr_eid[pos] = e;
}

__global__ __launch_bounds__(256)
void segptr_kernel(const int* __restrict__ batch, int nseg, int* __restrict__ ptr) {
    int s = blockIdx.x * 256 + threadIdx.x;
    if (s > nseg) return;
    int lo = 0, hi = N_NODES;
    while (lo < hi) {
        int mid = (lo + hi) >> 1;
        if (batch[mid] < s) lo = mid + 1; else hi = mid;
    }
    ptr[s] = lo;
}

// ---------------------------------------------------------------------------
// W [K][256] fp32  ->  WThi/WTlo [256][K] bf16 split
__global__ __launch_bounds__(256)
void wt_kernel(const float* __restrict__ W, unsigned short* __restrict__ WThi,
               unsigned short* __restrict__ WTlo, int K) {
    int id = blockIdx.x * 256 + threadIdx.x;
    if (id >= K * 256) return;
    int c = id / K, k = id - c * K;
    unsigned short h, l;
    split2(W[(size_t)k * 256 + c], h, l);
    WThi[id] = h;
    WTlo[id] = l;
}

// ---------------------------------------------------------------------------
// agg_e[n] = sum over incoming edges of relu(edge_attr[e])  [N,32]
__global__ __launch_bounds__(256)
void edge_gather_kernel(const float* __restrict__ ea, const int* __restrict__ row_ptr,
                        const int* __restrict__ csr_eid, float* __restrict__ agg_e) {
    int t = threadIdx.x;
    int g = t >> 3;
    int j = t & 7;
    int n = blockIdx.x * 32 + g;
    if (n >= N_NODES) return;
    int col = j << 2;
    float4 acc = {0.f, 0.f, 0.f, 0.f};
    int beg = row_ptr[n], end = row_ptr[n + 1];
    for (int e = beg; e < end; ++e) {
        int eid = csr_eid[e];
        float4 v = *(const float4*)(ea + (size_t)eid * DE + col);
        acc.x += fmaxf(v.x, 0.f);
        acc.y += fmaxf(v.y, 0.f);
        acc.z += fmaxf(v.z, 0.f);
        acc.w += fmaxf(v.w, 0.f);
    }
    *(float4*)(agg_e + (size_t)n * DE + col) = acc;
}

// agg[n][0:din] = xin[n] + sum relu(xin[src]);  agg[n][din:fin] = agg_e[n]
// If BNIN: xin is pre-BN h, apply x = scale*h + shift at load (per-column).
template <bool BNIN>
__global__ __launch_bounds__(256)
void gather_agg_kernel(const float* __restrict__ x, const int* __restrict__ row_ptr,
                       const int* __restrict__ csr_src, const float* __restrict__ agg_e,
                       float* __restrict__ agg, const float* __restrict__ bnsc,
                       const float* __restrict__ bnsh, int din, int fin, int gsize_log2) {
    int t = threadIdx.x;
    int g = t >> gsize_log2;
    int j = t & ((1 << gsize_log2) - 1);
    int n = blockIdx.x * (256 >> gsize_log2) + g;
    if (n >= N_NODES) return;
    int col = j << 2;
    float4 sc, sh;
    if (BNIN) {
        sc = *(const float4*)(bnsc + col);
        sh = *(const float4*)(bnsh + col);
    }
    float4 acc = *(const float4*)(x + (size_t)n * din + col);  // self term
    if (BNIN) {
        acc.x = fmaf(acc.x, sc.x, sh.x);
        acc.y = fmaf(acc.y, sc.y, sh.y);
        acc.z = fmaf(acc.z, sc.z, sh.z);
        acc.w = fmaf(acc.w, sc.w, sh.w);
    }
    int beg = row_ptr[n], end = row_ptr[n + 1];
    for (int e = beg; e < end; ++e) {
        int src = csr_src[e];
        float4 v = *(const float4*)(x + (size_t)src * din + col);
        if (BNIN) {
            v.x = fmaf(v.x, sc.x, sh.x);
            v.y = fmaf(v.y, sc.y, sh.y);
            v.z = fmaf(v.z, sc.z, sh.z);
            v.w = fmaf(v.w, sc.w, sh.w);
        }
        acc.x += fmaxf(v.x, 0.f);
        acc.y += fmaxf(v.y, 0.f);
        acc.z += fmaxf(v.z, 0.f);
        acc.w += fmaxf(v.w, 0.f);
    }
    *(float4*)(agg + (size_t)n * fin + col) = acc;
    if (j < 8) {
        float4 v = *(const float4*)(agg_e + (size_t)n * DE + (j << 2));
        *(float4*)(agg + (size_t)n * fin + din + (j << 2)) = v;
    }
}

// ---------------------------------------------------------------------------
// Split-bf16 MFMA GEMM: C = relu(A @ W + bias), fp32-equivalent accuracy via
// Ahi*Whi + Ahi*Wlo + Alo*Whi (lo*lo dropped).
// Block: 256 thr (4 waves), tile 64 rows x 256 cols, BK=32.
template <bool BN>
__global__ __launch_bounds__(256)
void gemm_mfma_kernel(const float* __restrict__ A, const unsigned short* __restrict__ WThi,
                      const unsigned short* __restrict__ WTlo,
                      const float* __restrict__ bias, float* __restrict__ C, int K,
                      float* __restrict__ bnsum) {
    __shared__ __align__(16) unsigned short sAhi[64 * 40];
    __shared__ __align__(16) unsigned short sAlo[64 * 40];
    __shared__ __align__(16) unsigned short sBhi[256 * 40];
    __shared__ __align__(16) unsigned short sBlo[256 * 40];
    const int t = threadIdx.x;
    const int l = t & 63;
    const int w = t >> 6;
    const int lr = l & 15;     // MFMA row/col within tile
    const int lq = l >> 4;     // quad
    const int row0 = blockIdx.x << 6;
    const int cb = w << 6;     // wave col base
    const int ar = t >> 2;     // A-staging row 0..63
    const int ac = t & 3;      // A-staging k-chunk 0..3

    f32x4 acc[4][4];
#pragma unroll
    for (int mt = 0; mt < 4; ++mt)
#pragma unroll
        for (int nt = 0; nt < 4; ++nt) acc[mt][nt] = (f32x4){0.f, 0.f, 0.f, 0.f};

    for (int k0 = 0; k0 < K; k0 += 32) {
        // stage A (64x32 fp32 -> hi/lo bf16)
        {
            float4 a0 = {0.f, 0.f, 0.f, 0.f}, a1 = {0.f, 0.f, 0.f, 0.f};
            int gr = row0 + ar;
            if (gr < N_NODES) {
                const float* ap = A + (size_t)gr * K + k0 + (ac << 3);
                a0 = *(const float4*)ap;
                a1 = *(const float4*)(ap + 4);
            }
            short8 hv, lv;
            unsigned short h, lo_;
            split2(a0.x, h, lo_); hv[0] = (short)h; lv[0] = (short)lo_;
            split2(a0.y, h, lo_); hv[1] = (short)h; lv[1] = (short)lo_;
            split2(a0.z, h, lo_); hv[2] = (short)h; lv[2] = (short)lo_;
            split2(a0.w, h, lo_); hv[3] = (short)h; lv[3] = (short)lo_;
            split2(a1.x, h, lo_); hv[4] = (short)h; lv[4] = (short)lo_;
            split2(a1.y, h, lo_); hv[5] = (short)h; lv[5] = (short)lo_;
            split2(a1.z, h, lo_); hv[6] = (short)h; lv[6] = (short)lo_;
            split2(a1.w, h, lo_); hv[7] = (short)h; lv[7] = (short)lo_;
            *(short8*)&sAhi[ar * 40 + (ac << 3)] = hv;
            *(short8*)&sAlo[ar * 40 + (ac << 3)] = lv;
        }
        // stage B (256 cols x 32 k, hi+lo pure copies)
#pragma unroll
        for (int i = 0; i < 4; ++i) {
            int c = t + (i << 8);
            int col = c >> 2, kc = c & 3;
            size_t goff = (size_t)col * K + k0 + (kc << 3);
            int soff = col * 40 + (kc << 3);
            *(short8*)&sBhi[soff] = *(const short8*)(WThi + goff);
            *(short8*)&sBlo[soff] = *(const short8*)(WTlo + goff);
        }
        __syncthreads();
        short8 afh[4], afl[4], bfh[4], bfl[4];
#pragma unroll
        for (int mt = 0; mt < 4; ++mt) {
            int soff = (mt * 16 + lr) * 40 + (lq << 3);
            afh[mt] = *(const short8*)&sAhi[soff];
            afl[mt] = *(const short8*)&sAlo[soff];
        }
#pragma unroll
        for (int nt = 0; nt < 4; ++nt) {
            int soff = (cb + nt * 16 + lr) * 40 + (lq << 3);
            bfh[nt] = *(const short8*)&sBhi[soff];
            bfl[nt] = *(const short8*)&sBlo[soff];
        }
#pragma unroll
        for (int mt = 0; mt < 4; ++mt)
#pragma unroll
            for (int nt = 0; nt < 4; ++nt) {
                acc[mt][nt] = __builtin_amdgcn_mfma_f32_16x16x32_bf16(
                    afl[mt], bfh[nt], acc[mt][nt], 0, 0, 0);
                acc[mt][nt] = __builtin_amdgcn_mfma_f32_16x16x32_bf16(
                    afh[mt], bfl[nt], acc[mt][nt], 0, 0, 0);
                acc[mt][nt] = __builtin_amdgcn_mfma_f32_16x16x32_bf16(
                    afh[mt], bfh[nt], acc[mt][nt], 0, 0, 0);
            }
        __syncthreads();
    }

    // epilogue: bias + relu + store (+BN stats)
    float b4[4];
#pragma unroll
    for (int nt = 0; nt < 4; ++nt) b4[nt] = bias[cb + nt * 16 + lr];
    float s4[4] = {0.f, 0.f, 0.f, 0.f}, q4[4] = {0.f, 0.f, 0.f, 0.f};
#pragma unroll
    for (int mt = 0; mt < 4; ++mt) {
#pragma unroll
        for (int i = 0; i < 4; ++i) {
            int row = row0 + mt * 16 + lq * 4 + i;   // C/D: row = quad*4 + reg
            if (row < N_NODES) {
                float* cp = C + (size_t)row * 256 + cb + lr;
#pragma unroll
                for (int nt = 0; nt < 4; ++nt) {
                    float o = fmaxf(acc[mt][nt][i] + b4[nt], 0.f);
                    cp[nt * 16] = o;
                    if (BN) { s4[nt] += o; q4[nt] += o * o; }
                }
            }
        }
    }
    if (BN) {
#pragma unroll
        for (int nt = 0; nt < 4; ++nt) {
            s4[nt] += __shfl_xor(s4[nt], 16); s4[nt] += __shfl_xor(s4[nt], 32);
            q4[nt] += __shfl_xor(q4[nt], 16); q4[nt] += __shfl_xor(q4[nt], 32);
        }
        float* sRed = (float*)sAhi;
        __syncthreads();
        if (lq == 0) {
#pragma unroll
            for (int nt = 0; nt < 4; ++nt) {
                int col = cb + nt * 16 + lr;
                sRed[col] = s4[nt];
                sRed[256 + col] = q4[nt];
            }
        }
        __syncthreads();
        atomicAdd(&bnsum[t], sRed[t]);
        atomicAdd(&bnsum[t + 256], sRed[t + 256]);
    }
}

__global__ void bn_finalize_kernel(const float* __restrict__ sum, const float* __restrict__ sumsq,
                                   const float* __restrict__ g, const float* __restrict__ beta,
                                   float* __restrict__ scale, float* __restrict__ shift) {
    int c = threadIdx.x;
    float mu = sum[c] * (1.0f / N_NODES);
    float var = sumsq[c] * (1.0f / N_NODES) - mu * mu;
    float rstd = rsqrtf(var + 1e-5f);
    float sc = g[c] * rstd;
    scale[c] = sc;
    shift[c] = beta[c] - mu * sc;
}

// segmented sqrt-pool with BN applied at load; no atomics
__global__ __launch_bounds__(256)
void pool_seg_kernel(const float* __restrict__ h, const int* __restrict__ ptr,
                     const float* __restrict__ bnsc, const float* __restrict__ bnsh,
                     float* __restrict__ out, int nseg) {
    int t = threadIdx.x;
    int g = t >> 6;
    int j = t & 63;
    int s = blockIdx.x * 4 + g;
    if (s >= nseg) return;
    int beg = ptr[s], end = ptr[s + 1];
    int col = j << 2;
    float4 sc = *(const float4*)(bnsc + col);
    float4 sh = *(const float4*)(bnsh + col);
    float4 acc = {0.f, 0.f, 0.f, 0.f};
    for (int i = beg; i < end; ++i) {
        float4 v = *(const float4*)(h + (size_t)i * 256 + col);
        acc.x += fmaf(v.x, sc.x, sh.x);
        acc.y += fmaf(v.y, sc.y, sh.y);
        acc.z += fmaf(v.z, sc.z, sh.z);
        acc.w += fmaf(v.w, sc.w, sh.w);
    }
    float w = rsqrtf(fmaxf((float)(end - beg), 1.0f));
    float4 o = {acc.x * w, acc.y * w, acc.z * w, acc.w * w};
    *(float4*)(out + (size_t)s * 256 + col) = o;
}

// ---------------------------------------------------------------------------
extern "C" void kernel_launch(void* const* d_in, const int* in_sizes, int n_in,
                              void* d_out, int out_size, void* d_ws, size_t ws_size,
                              hipStream_t stream) {
    const float* x  = (const float*)d_in[0];
    const float* ea = (const float*)d_in[1];
    const int*   ei = (const int*)d_in[2];
    const int*   fb = (const int*)d_in[3];
    const int*   gb = (const int*)d_in[4];
    const float* W1[3]   = {(const float*)d_in[5],  (const float*)d_in[11], (const float*)d_in[17]};
    const float* B1[3]   = {(const float*)d_in[6],  (const float*)d_in[12], (const float*)d_in[18]};
    const float* W2[3]   = {(const float*)d_in[7],  (const float*)d_in[13], (const float*)d_in[19]};
    const float* B2[3]   = {(const float*)d_in[8],  (const float*)d_in[14], (const float*)d_in[20]};
    const float* G[3]    = {(const float*)d_in[9],  (const float*)d_in[15], (const float*)d_in[21]};
    const float* BETA[3] = {(const float*)d_in[10], (const float*)d_in[16], (const float*)d_in[22]};

    const int FIN[3] = {160, 288, 288};
    const int NBLK = (N_NODES + 255) / 256;      // 196 (scan blocks)

    float* ws = (float*)d_ws;
    size_t off = 0;
    float* agg   = ws + off; off += (size_t)N_NODES * 288;
    float* h1    = ws + off; off += (size_t)N_NODES * 256;
    float* xbuf  = ws + off; off += (size_t)N_NODES * 256;
    float* agg_e = ws + off; off += (size_t)N_NODES * DE;
    float* bn    = ws + off; off += 3 * 1024;
    unsigned short* w1hi[3]; unsigned short* w1lo[3];
    unsigned short* w2hi[3]; unsigned short* w2lo[3];
    {
        unsigned short* sw = (unsigned short*)(ws + off);
        unsigned short* sw0 = sw;
        for (int l = 0; l < 3; ++l) {
            w1hi[l] = sw; sw += 256 * FIN[l];
            w1lo[l] = sw; sw += 256 * FIN[l];
        }
        for (int l = 0; l < 3; ++l) {
            w2hi[l] = sw; sw += 256 * 256;
            w2lo[l] = sw; sw += 256 * 256;
        }
        off += (size_t)(sw - sw0 + 1) / 2;
    }
    int* iw      = (int*)(ws + off);
    int* row_ptr = iw;                     iw += N_NODES + 1;
    int* deg     = iw;                     iw += N_NODES;
    int* fill    = iw;                     iw += N_NODES;
    int* csr_src = iw;                     iw += N_EDGES;
    int* csr_eid = iw;                     iw += N_EDGES;
    int* frag_ptr = iw;                    iw += N_FRAG + 1;
    int* graph_ptr = iw;                   iw += N_GRAPH + 1;
    int* bsum    = iw;                     iw += NBLK;

    hipMemsetAsync(deg, 0, 2 * N_NODES * sizeof(int), stream);
    hipMemsetAsync(bn, 0, 3 * 1024 * sizeof(float), stream);

    // weight transpose + bf16 hi/lo split (once per layer)
    for (int l = 0; l < 3; ++l) {
        wt_kernel<<<(FIN[l] * 256 + 255) / 256, 256, 0, stream>>>(W1[l], w1hi[l], w1lo[l], FIN[l]);
        wt_kernel<<<(256 * 256 + 255) / 256, 256, 0, stream>>>(W2[l], w2hi[l], w2lo[l], 256);
    }

    // CSR build (hierarchical scan, no single-block serialization)
    count_deg_kernel<<<(N_EDGES + 255) / 256, 256, 0, stream>>>(ei, deg);
    block_sum_kernel<<<NBLK, 256, 0, stream>>>(deg, bsum);
    top_scan_kernel<<<1, 256, 0, stream>>>(bsum, NBLK);
    final_scan_kernel<<<NBLK, 256, 0, stream>>>(deg, bsum, row_ptr);
    fill_csr_kernel<<<(N_EDGES + 255) / 256, 256, 0, stream>>>(ei, row_ptr, fill, csr_src, csr_eid);

    segptr_kernel<<<(N_FRAG + 1 + 255) / 256, 256, 0, stream>>>(fb, N_FRAG, frag_ptr);
    segptr_kernel<<<(N_GRAPH + 1 + 255) / 256, 256, 0, stream>>>(gb, N_GRAPH, graph_ptr);

    edge_gather_kernel<<<(N_NODES + 31) / 32, 256, 0, stream>>>(ea, row_ptr, csr_eid, agg_e);

    const int nblk_gemm = (N_NODES + 63) / 64;
    const float* xin = x;
    for (int l = 0; l < 3; ++l) {
        const int din = (l == 0) ? 128 : 256;
        const int fin = FIN[l];
        const int gl2 = (din == 128) ? 5 : 6;
        const int npb = 256 >> gl2;
        float* bsumL = bn + l * 1024;
        float* bscale = bsumL + 512;
        float* bshift = bsumL + 768;
        const float* psc = (l > 0) ? bn + (l - 1) * 1024 + 512 : nullptr;  // prev layer BN
        const float* psh = (l > 0) ? bn + (l - 1) * 1024 + 768 : nullptr;

        if (l == 0)
            gather_agg_kernel<false><<<(N_NODES + npb - 1) / npb, 256, 0, stream>>>(
                xin, row_ptr, csr_src, agg_e, agg, nullptr, nullptr, din, fin, gl2);
        else
            gather_agg_kernel<true><<<(N_NODES + npb - 1) / npb, 256, 0, stream>>>(
                xin, row_ptr, csr_src, agg_e, agg, psc, psh, din, fin, gl2);
        gemm_mfma_kernel<false><<<nblk_gemm, 256, 0, stream>>>(
            agg, w1hi[l], w1lo[l], B1[l], h1, fin, nullptr);
        gemm_mfma_kernel<true><<<nblk_gemm, 256, 0, stream>>>(
            h1, w2hi[l], w2lo[l], B2[l], xbuf, 256, bsumL);
        bn_finalize_kernel<<<1, 256, 0, stream>>>(bsumL, bsumL + 256, G[l], BETA[l], bscale, bshift);
        xin = xbuf;   // pre-BN h; BN applied by next consumer
    }

    const float* fsc = bn + 2 * 1024 + 512;   // layer-2 BN scale/shift
    const float* fsh = bn + 2 * 1024 + 768;
    pool_seg_kernel<<<(N_FRAG + 3) / 4, 256, 0, stream>>>(xbuf, frag_ptr, fsc, fsh,
                                                          (float*)d_out, N_FRAG);
    pool_seg_kernel<<<(N_GRAPH + 3) / 4, 256, 0, stream>>>(xbuf, graph_ptr, fsc, fsh,
                                                           (float*)d_out + (size_t)N_FRAG * 256, N_GRAPH);
}

// Round 6
// 584.852 us; speedup vs baseline: 6.4254x; 1.0436x over previous
//
#include <hip/hip_runtime.h>

#define N_NODES 50000
#define N_EDGES 200000
#define DE 32
#define N_FRAG 10000
#define N_GRAPH 2000

typedef __attribute__((ext_vector_type(8))) short short8;
typedef __attribute__((ext_vector_type(4))) float f32x4;

__device__ __forceinline__ unsigned short f2bf(float f) {
    unsigned u = __float_as_uint(f);
    u += 0x7FFF + ((u >> 16) & 1);      // RNE (no NaN inputs here)
    return (unsigned short)(u >> 16);
}

// split x = hi + lo (hi=bf16(x), lo=bf16(x-hi)); x-hi exact in fp32
__device__ __forceinline__ void split2(float f, unsigned short& h, unsigned short& l) {
    h = f2bf(f);
    float fh = __uint_as_float((unsigned)h << 16);
    l = f2bf(f - fh);
}

// ---------------------------------------------------------------------------
// CSR build: in-degree count, hierarchical scan, fill
__global__ __launch_bounds__(256)
void count_deg_kernel(const int* __restrict__ ei, int* __restrict__ deg) {
    int e = blockIdx.x * 256 + threadIdx.x;
    if (e < N_EDGES) atomicAdd(&deg[ei[N_EDGES + e]], 1);
}

__global__ __launch_bounds__(256)
void block_sum_kernel(const int* __restrict__ deg, int* __restrict__ bsum) {
    int i = blockIdx.x * 256 + threadIdx.x;
    int v = (i < N_NODES) ? deg[i] : 0;
#pragma unroll
    for (int o = 1; o < 64; o <<= 1) v += __shfl_xor(v, o);
    __shared__ int wsum[4];
    if ((threadIdx.x & 63) == 0) wsum[threadIdx.x >> 6] = v;
    __syncthreads();
    if (threadIdx.x == 0) bsum[blockIdx.x] = wsum[0] + wsum[1] + wsum[2] + wsum[3];
}

__global__ __launch_bounds__(256)
void top_scan_kernel(int* __restrict__ bsum, int nb) {
    __shared__ int s[256];
    int t = threadIdx.x;
    s[t] = (t < nb) ? bsum[t] : 0;
    __syncthreads();
    for (int o = 1; o < 256; o <<= 1) {
        int v = s[t];
        int a = (t >= o) ? s[t - o] : 0;
        __syncthreads();
        s[t] = v + a;
        __syncthreads();
    }
    if (t < nb) bsum[t] = (t > 0) ? s[t - 1] : 0;
}

__global__ __launch_bounds__(256)
void final_scan_kernel(const int* __restrict__ deg, const int* __restrict__ bsum,
                       int* __restrict__ ptr) {
    __shared__ int s[256];
    int i = blockIdx.x * 256 + threadIdx.x;
    int t = threadIdx.x;
    int v = (i < N_NODES) ? deg[i] : 0;
    s[t] = v;
    __syncthreads();
    for (int o = 1; o < 256; o <<= 1) {
        int x = s[t];
        int a = (t >= o) ? s[t - o] : 0;
        __syncthreads();
        s[t] = x + a;
        __syncthreads();
    }
    int incl = s[t];
    int base = bsum[blockIdx.x];
    if (i < N_NODES) ptr[i] = base + incl - v;
    if (i == N_NODES - 1) ptr[N_NODES] = base + incl;
}

__global__ __launch_bounds__(256)
void fill_csr_kernel(const int* __restrict__ ei, const int* __restrict__ row_ptr,
                     int* __restrict__ fill, int* __restrict__ csr_src,
                     int* __restrict__ csr_eid) {
    int e = blockIdx.x * 256 + threadIdx.x;
    if (e >= N_EDGES) return;
    int dst = ei[N_EDGES + e];
    int pos = row_ptr[dst] + atomicAdd(&fill[dst], 1);
    csr_src[pos] = ei[e];
    csr_eid[pos] = e;
}

__global__ __launch_bounds__(256)
void segptr_kernel(const int* __restrict__ batch, int nseg, int* __restrict__ ptr) {
    int s = blockIdx.x * 256 + threadIdx.x;
    if (s > nseg) return;
    int lo = 0, hi = N_NODES;
    while (lo < hi) {
        int mid = (lo + hi) >> 1;
        if (batch[mid] < s) lo = mid + 1; else hi = mid;
    }
    ptr[s] = lo;
}

// ---------------------------------------------------------------------------
// W [K][256] fp32 -> fragment-swizzled BShi/BSlo:
// BS[kt][cg][lane][j] = split(W[kt*32 + (lane>>4)*8 + j][cg*16 + (lane&15)])
// so a wave's B-fragment (16 cols x 32 k) is one contiguous 1 KB read.
__global__ __launch_bounds__(256)
void bs_kernel(const float* __restrict__ W, unsigned short* __restrict__ BShi,
               unsigned short* __restrict__ BSlo, int K) {
    int id = blockIdx.x * 256 + threadIdx.x;
    if (id >= K * 256) return;
    int j  = id & 7;
    int l  = (id >> 3) & 63;
    int cg = (id >> 9) & 15;
    int kt = id >> 13;
    int col = cg * 16 + (l & 15);
    int k   = kt * 32 + (l >> 4) * 8 + j;
    unsigned short h, lo;
    split2(W[(size_t)k * 256 + col], h, lo);
    BShi[id] = h;
    BSlo[id] = lo;
}

// ---------------------------------------------------------------------------
// agg_e[n] = sum over incoming edges of relu(edge_attr[e])  [N,32]
__global__ __launch_bounds__(256)
void edge_gather_kernel(const float* __restrict__ ea, const int* __restrict__ row_ptr,
                        const int* __restrict__ csr_eid, float* __restrict__ agg_e) {
    int t = threadIdx.x;
    int g = t >> 3;
    int j = t & 7;
    int n = blockIdx.x * 32 + g;
    if (n >= N_NODES) return;
    int col = j << 2;
    float4 acc = {0.f, 0.f, 0.f, 0.f};
    int beg = row_ptr[n], end = row_ptr[n + 1];
    for (int e = beg; e < end; ++e) {
        int eid = csr_eid[e];
        float4 v = *(const float4*)(ea + (size_t)eid * DE + col);
        acc.x += fmaxf(v.x, 0.f);
        acc.y += fmaxf(v.y, 0.f);
        acc.z += fmaxf(v.z, 0.f);
        acc.w += fmaxf(v.w, 0.f);
    }
    *(float4*)(agg_e + (size_t)n * DE + col) = acc;
}

// agg[n][0:din] = xin[n] + sum relu(xin[src]);  agg[n][din:fin] = agg_e[n]
// If BNIN: xin is pre-BN h, apply x = scale*h + shift at load (per-column).
template <bool BNIN>
__global__ __launch_bounds__(256)
void gather_agg_kernel(const float* __restrict__ x, const int* __restrict__ row_ptr,
                       const int* __restrict__ csr_src, const float* __restrict__ agg_e,
                       float* __restrict__ agg, const float* __restrict__ bnsc,
                       const float* __restrict__ bnsh, int din, int fin, int gsize_log2) {
    int t = threadIdx.x;
    int g = t >> gsize_log2;
    int j = t & ((1 << gsize_log2) - 1);
    int n = blockIdx.x * (256 >> gsize_log2) + g;
    if (n >= N_NODES) return;
    int col = j << 2;
    float4 sc, sh;
    if (BNIN) {
        sc = *(const float4*)(bnsc + col);
        sh = *(const float4*)(bnsh + col);
    }
    float4 acc = *(const float4*)(x + (size_t)n * din + col);  // self term
    if (BNIN) {
        acc.x = fmaf(acc.x, sc.x, sh.x);
        acc.y = fmaf(acc.y, sc.y, sh.y);
        acc.z = fmaf(acc.z, sc.z, sh.z);
        acc.w = fmaf(acc.w, sc.w, sh.w);
    }
    int beg = row_ptr[n], end = row_ptr[n + 1];
    for (int e = beg; e < end; ++e) {
        int src = csr_src[e];
        float4 v = *(const float4*)(x + (size_t)src * din + col);
        if (BNIN) {
            v.x = fmaf(v.x, sc.x, sh.x);
            v.y = fmaf(v.y, sc.y, sh.y);
            v.z = fmaf(v.z, sc.z, sh.z);
            v.w = fmaf(v.w, sc.w, sh.w);
        }
        acc.x += fmaxf(v.x, 0.f);
        acc.y += fmaxf(v.y, 0.f);
        acc.z += fmaxf(v.z, 0.f);
        acc.w += fmaxf(v.w, 0.f);
    }
    *(float4*)(agg + (size_t)n * fin + col) = acc;
    if (j < 8) {
        float4 v = *(const float4*)(agg_e + (size_t)n * DE + (j << 2));
        *(float4*)(agg + (size_t)n * fin + din + (j << 2)) = v;
    }
}

// ---------------------------------------------------------------------------
// Split-bf16 MFMA GEMM v3: C = relu(A @ W + bias).
// A staged fp32->hi/lo bf16 in LDS (10 KB); B read as pre-swizzled fragments
// directly from global (L2-resident, coalesced 1KB/wave) — no B LDS.
// Block: 256 thr (4 waves), tile 64 rows x 256 cols, BK=32.
template <bool BN>
__global__ __launch_bounds__(256)
void gemm_mfma_kernel(const float* __restrict__ A, const unsigned short* __restrict__ BShi,
                      const unsigned short* __restrict__ BSlo,
                      const float* __restrict__ bias, float* __restrict__ C, int K,
                      float* __restrict__ bnsum) {
    __shared__ __align__(16) unsigned short sAhi[64 * 40];
    __shared__ __align__(16) unsigned short sAlo[64 * 40];
    const int t = threadIdx.x;
    const int l = t & 63;
    const int w = t >> 6;
    const int lr = l & 15;     // MFMA row/col within tile
    const int lq = l >> 4;     // quad
    const int row0 = blockIdx.x << 6;
    const int cb = w << 6;     // wave col base
    const int ar = t >> 2;     // A-staging row 0..63
    const int ac = t & 3;      // A-staging k-chunk 0..3

    f32x4 acc[4][4];
#pragma unroll
    for (int mt = 0; mt < 4; ++mt)
#pragma unroll
        for (int nt = 0; nt < 4; ++nt) acc[mt][nt] = (f32x4){0.f, 0.f, 0.f, 0.f};

    const int nkt = K >> 5;
    for (int kt = 0; kt < nkt; ++kt) {
        // B fragments straight from global (issue first; in flight during A staging)
        short8 bfh[4], bfl[4];
        const size_t bbase = ((size_t)(kt * 16 + (w << 2))) * 512 + (l << 3);
#pragma unroll
        for (int nt = 0; nt < 4; ++nt) {
            bfh[nt] = *(const short8*)(BShi + bbase + nt * 512);
            bfl[nt] = *(const short8*)(BSlo + bbase + nt * 512);
        }
        // stage A (64x32 fp32 -> hi/lo bf16)
        {
            float4 a0 = {0.f, 0.f, 0.f, 0.f}, a1 = {0.f, 0.f, 0.f, 0.f};
            int gr = row0 + ar;
            if (gr < N_NODES) {
                const float* ap = A + (size_t)gr * K + (kt << 5) + (ac << 3);
                a0 = *(const float4*)ap;
                a1 = *(const float4*)(ap + 4);
            }
            short8 hv, lv;
            unsigned short h, lo_;
            split2(a0.x, h, lo_); hv[0] = (short)h; lv[0] = (short)lo_;
            split2(a0.y, h, lo_); hv[1] = (short)h; lv[1] = (short)lo_;
            split2(a0.z, h, lo_); hv[2] = (short)h; lv[2] = (short)lo_;
            split2(a0.w, h, lo_); hv[3] = (short)h; lv[3] = (short)lo_;
            split2(a1.x, h, lo_); hv[4] = (short)h; lv[4] = (short)lo_;
            split2(a1.y, h, lo_); hv[5] = (short)h; lv[5] = (short)lo_;
            split2(a1.z, h, lo_); hv[6] = (short)h; lv[6] = (short)lo_;
            split2(a1.w, h, lo_); hv[7] = (short)h; lv[7] = (short)lo_;
            *(short8*)&sAhi[ar * 40 + (ac << 3)] = hv;
            *(short8*)&sAlo[ar * 40 + (ac << 3)] = lv;
        }
        __syncthreads();
        short8 afh[4], afl[4];
#pragma unroll
        for (int mt = 0; mt < 4; ++mt) {
            int soff = (mt * 16 + lr) * 40 + (lq << 3);
            afh[mt] = *(const short8*)&sAhi[soff];
            afl[mt] = *(const short8*)&sAlo[soff];
        }
#pragma unroll
        for (int mt = 0; mt < 4; ++mt)
#pragma unroll
            for (int nt = 0; nt < 4; ++nt) {
                acc[mt][nt] = __builtin_amdgcn_mfma_f32_16x16x32_bf16(
                    afl[mt], bfh[nt], acc[mt][nt], 0, 0, 0);
                acc[mt][nt] = __builtin_amdgcn_mfma_f32_16x16x32_bf16(
                    afh[mt], bfl[nt], acc[mt][nt], 0, 0, 0);
                acc[mt][nt] = __builtin_amdgcn_mfma_f32_16x16x32_bf16(
                    afh[mt], bfh[nt], acc[mt][nt], 0, 0, 0);
            }
        __syncthreads();
    }

    // epilogue: bias + relu + store (+BN stats)
    float b4[4];
#pragma unroll
    for (int nt = 0; nt < 4; ++nt) b4[nt] = bias[cb + nt * 16 + lr];
    float s4[4] = {0.f, 0.f, 0.f, 0.f}, q4[4] = {0.f, 0.f, 0.f, 0.f};
#pragma unroll
    for (int mt = 0; mt < 4; ++mt) {
#pragma unroll
        for (int i = 0; i < 4; ++i) {
            int row = row0 + mt * 16 + lq * 4 + i;   // C/D: row = quad*4 + reg
            if (row < N_NODES) {
                float* cp = C + (size_t)row * 256 + cb + lr;
#pragma unroll
                for (int nt = 0; nt < 4; ++nt) {
                    float o = fmaxf(acc[mt][nt][i] + b4[nt], 0.f);
                    cp[nt * 16] = o;
                    if (BN) { s4[nt] += o; q4[nt] += o * o; }
                }
            }
        }
    }
    if (BN) {
#pragma unroll
        for (int nt = 0; nt < 4; ++nt) {
            s4[nt] += __shfl_xor(s4[nt], 16); s4[nt] += __shfl_xor(s4[nt], 32);
            q4[nt] += __shfl_xor(q4[nt], 16); q4[nt] += __shfl_xor(q4[nt], 32);
        }
        float* sRed = (float*)sAhi;   // 5120 B >= 512 floats
        __syncthreads();
        if (lq == 0) {
#pragma unroll
            for (int nt = 0; nt < 4; ++nt) {
                int col = cb + nt * 16 + lr;
                sRed[col] = s4[nt];
                sRed[256 + col] = q4[nt];
            }
        }
        __syncthreads();
        atomicAdd(&bnsum[t], sRed[t]);
        atomicAdd(&bnsum[t + 256], sRed[t + 256]);
    }
}

__global__ void bn_finalize_kernel(const float* __restrict__ sum, const float* __restrict__ sumsq,
                                   const float* __restrict__ g, const float* __restrict__ beta,
                                   float* __restrict__ scale, float* __restrict__ shift) {
    int c = threadIdx.x;
    float mu = sum[c] * (1.0f / N_NODES);
    float var = sumsq[c] * (1.0f / N_NODES) - mu * mu;
    float rstd = rsqrtf(var + 1e-5f);
    float sc = g[c] * rstd;
    scale[c] = sc;
    shift[c] = beta[c] - mu * sc;
}

// segmented sqrt-pool with BN applied at load; no atomics
__global__ __launch_bounds__(256)
void pool_seg_kernel(const float* __restrict__ h, const int* __restrict__ ptr,
                     const float* __restrict__ bnsc, const float* __restrict__ bnsh,
                     float* __restrict__ out, int nseg) {
    int t = threadIdx.x;
    int g = t >> 6;
    int j = t & 63;
    int s = blockIdx.x * 4 + g;
    if (s >= nseg) return;
    int beg = ptr[s], end = ptr[s + 1];
    int col = j << 2;
    float4 sc = *(const float4*)(bnsc + col);
    float4 sh = *(const float4*)(bnsh + col);
    float4 acc = {0.f, 0.f, 0.f, 0.f};
    for (int i = beg; i < end; ++i) {
        float4 v = *(const float4*)(h + (size_t)i * 256 + col);
        acc.x += fmaf(v.x, sc.x, sh.x);
        acc.y += fmaf(v.y, sc.y, sh.y);
        acc.z += fmaf(v.z, sc.z, sh.z);
        acc.w += fmaf(v.w, sc.w, sh.w);
    }
    float w = rsqrtf(fmaxf((float)(end - beg), 1.0f));
    float4 o = {acc.x * w, acc.y * w, acc.z * w, acc.w * w};
    *(float4*)(out + (size_t)s * 256 + col) = o;
}

// ---------------------------------------------------------------------------
extern "C" void kernel_launch(void* const* d_in, const int* in_sizes, int n_in,
                              void* d_out, int out_size, void* d_ws, size_t ws_size,
                              hipStream_t stream) {
    const float* x  = (const float*)d_in[0];
    const float* ea = (const float*)d_in[1];
    const int*   ei = (const int*)d_in[2];
    const int*   fb = (const int*)d_in[3];
    const int*   gb = (const int*)d_in[4];
    const float* W1[3]   = {(const float*)d_in[5],  (const float*)d_in[11], (const float*)d_in[17]};
    const float* B1[3]   = {(const float*)d_in[6],  (const float*)d_in[12], (const float*)d_in[18]};
    const float* W2[3]   = {(const float*)d_in[7],  (const float*)d_in[13], (const float*)d_in[19]};
    const float* B2[3]   = {(const float*)d_in[8],  (const float*)d_in[14], (const float*)d_in[20]};
    const float* G[3]    = {(const float*)d_in[9],  (const float*)d_in[15], (const float*)d_in[21]};
    const float* BETA[3] = {(const float*)d_in[10], (const float*)d_in[16], (const float*)d_in[22]};

    const int FIN[3] = {160, 288, 288};
    const int NBLK = (N_NODES + 255) / 256;      // scan blocks

    float* ws = (float*)d_ws;
    size_t off = 0;
    float* agg   = ws + off; off += (size_t)N_NODES * 288;
    float* h1    = ws + off; off += (size_t)N_NODES * 256;
    float* xbuf  = ws + off; off += (size_t)N_NODES * 256;
    float* agg_e = ws + off; off += (size_t)N_NODES * DE;
    float* bn    = ws + off; off += 3 * 1024;
    unsigned short* w1hi[3]; unsigned short* w1lo[3];
    unsigned short* w2hi[3]; unsigned short* w2lo[3];
    {
        unsigned short* sw = (unsigned short*)(ws + off);
        unsigned short* sw0 = sw;
        for (int l = 0; l < 3; ++l) {
            w1hi[l] = sw; sw += 256 * FIN[l];
            w1lo[l] = sw; sw += 256 * FIN[l];
        }
        for (int l = 0; l < 3; ++l) {
            w2hi[l] = sw; sw += 256 * 256;
            w2lo[l] = sw; sw += 256 * 256;
        }
        off += (size_t)(sw - sw0 + 1) / 2;
    }
    int* iw      = (int*)(ws + off);
    int* row_ptr = iw;                     iw += N_NODES + 1;
    int* deg     = iw;                     iw += N_NODES;
    int* fill    = iw;                     iw += N_NODES;
    int* csr_src = iw;                     iw += N_EDGES;
    int* csr_eid = iw;                     iw += N_EDGES;
    int* frag_ptr = iw;                    iw += N_FRAG + 1;
    int* graph_ptr = iw;                   iw += N_GRAPH + 1;
    int* bsum    = iw;                     iw += NBLK;

    hipMemsetAsync(deg, 0, 2 * N_NODES * sizeof(int), stream);
    hipMemsetAsync(bn, 0, 3 * 1024 * sizeof(float), stream);

    // weight fragment-swizzle + bf16 hi/lo split (once per layer)
    for (int l = 0; l < 3; ++l) {
        bs_kernel<<<(FIN[l] * 256 + 255) / 256, 256, 0, stream>>>(W1[l], w1hi[l], w1lo[l], FIN[l]);
        bs_kernel<<<(256 * 256 + 255) / 256, 256, 0, stream>>>(W2[l], w2hi[l], w2lo[l], 256);
    }

    // CSR build (hierarchical scan)
    count_deg_kernel<<<(N_EDGES + 255) / 256, 256, 0, stream>>>(ei, deg);
    block_sum_kernel<<<NBLK, 256, 0, stream>>>(deg, bsum);
    top_scan_kernel<<<1, 256, 0, stream>>>(bsum, NBLK);
    final_scan_kernel<<<NBLK, 256, 0, stream>>>(deg, bsum, row_ptr);
    fill_csr_kernel<<<(N_EDGES + 255) / 256, 256, 0, stream>>>(ei, row_ptr, fill, csr_src, csr_eid);

    segptr_kernel<<<(N_FRAG + 1 + 255) / 256, 256, 0, stream>>>(fb, N_FRAG, frag_ptr);
    segptr_kernel<<<(N_GRAPH + 1 + 255) / 256, 256, 0, stream>>>(gb, N_GRAPH, graph_ptr);

    edge_gather_kernel<<<(N_NODES + 31) / 32, 256, 0, stream>>>(ea, row_ptr, csr_eid, agg_e);

    const int nblk_gemm = (N_NODES + 63) / 64;
    const float* xin = x;
    for (int l = 0; l < 3; ++l) {
        const int din = (l == 0) ? 128 : 256;
        const int fin = FIN[l];
        const int gl2 = (din == 128) ? 5 : 6;
        const int npb = 256 >> gl2;
        float* bsumL = bn + l * 1024;
        float* bscale = bsumL + 512;
        float* bshift = bsumL + 768;
        const float* psc = (l > 0) ? bn + (l - 1) * 1024 + 512 : nullptr;  // prev layer BN
        const float* psh = (l > 0) ? bn + (l - 1) * 1024 + 768 : nullptr;

        if (l == 0)
            gather_agg_kernel<false><<<(N_NODES + npb - 1) / npb, 256, 0, stream>>>(
                xin, row_ptr, csr_src, agg_e, agg, nullptr, nullptr, din, fin, gl2);
        else
            gather_agg_kernel<true><<<(N_NODES + npb - 1) / npb, 256, 0, stream>>>(
                xin, row_ptr, csr_src, agg_e, agg, psc, psh, din, fin, gl2);
        gemm_mfma_kernel<false><<<nblk_gemm, 256, 0, stream>>>(
            agg, w1hi[l], w1lo[l], B1[l], h1, fin, nullptr);
        gemm_mfma_kernel<true><<<nblk_gemm, 256, 0, stream>>>(
            h1, w2hi[l], w2lo[l], B2[l], xbuf, 256, bsumL);
        bn_finalize_kernel<<<1, 256, 0, stream>>>(bsumL, bsumL + 256, G[l], BETA[l], bscale, bshift);
        xin = xbuf;   // pre-BN h; BN applied by next consumer
    }

    const float* fsc = bn + 2 * 1024 + 512;   // layer-2 BN scale/shift
    const float* fsh = bn + 2 * 1024 + 768;
    pool_seg_kernel<<<(N_FRAG + 3) / 4, 256, 0, stream>>>(xbuf, frag_ptr, fsc, fsh,
                                                          (float*)d_out, N_FRAG);
    pool_seg_kernel<<<(N_GRAPH + 3) / 4, 256, 0, stream>>>(xbuf, graph_ptr, fsc, fsh,
                                                           (float*)d_out + (size_t)N_FRAG * 256, N_GRAPH);
}